// Round 1
// baseline (21458.205 us; speedup 1.0000x reference)
//
#include <hip/hip_runtime.h>
#include <math.h>

#define NN_ 200000
#define EE_ 400000
#define HH  96
#define LL  6
#define BB  4096
#define CHUNK 50000

static inline int cdiv(int a, int b) { return (a + b - 1) / b; }

__device__ __forceinline__ float sigmoidf_(float x) { return 1.0f / (1.0f + expf(-x)); }

// ---------------------------------------------------------------------------
// Generic fp32 tiled GEMM: C[M,N] = A[M,K] @ B[K,N] (+bias, +relu)
// A is read through a split: A[n,k] = k < K0 ? A0[n*K0+k] : A1[n*(K-K0)+(k-K0)]
// (pass A1=A0, K0=K for a plain GEMM). Requires K%16==0, K0%4==0, N%4==0.
// ---------------------------------------------------------------------------
#define BM 64
#define BN 64
#define BK 16
__global__ __launch_bounds__(256) void gemm_k(
    const float* __restrict__ A0, const float* __restrict__ A1, int K0,
    const float* __restrict__ B, const float* __restrict__ bias,
    float* __restrict__ C, int M, int N, int K, int doRelu)
{
    __shared__ float As[BK][BM];
    __shared__ float Bs[BK][BN];
    int tid = threadIdx.x;
    int m0 = blockIdx.y * BM;
    int n0 = blockIdx.x * BN;
    int tx = tid & 15;       // n direction
    int ty = tid >> 4;       // m direction
    float acc[4][4] = {};

    for (int k0 = 0; k0 < K; k0 += BK) {
        // load A tile (64 rows x 16 k), float4 per thread
        {
            int row = tid >> 2;
            int kq  = (tid & 3) * 4;
            int gm  = m0 + row;
            int gk  = k0 + kq;
            float4 v = make_float4(0.f, 0.f, 0.f, 0.f);
            if (gm < M) {
                const float* src;
                if (gk < K0) src = A0 + (size_t)gm * K0 + gk;
                else         src = A1 + (size_t)gm * (size_t)(K - K0) + (gk - K0);
                v = *(const float4*)src;
            }
            As[kq + 0][row] = v.x;
            As[kq + 1][row] = v.y;
            As[kq + 2][row] = v.z;
            As[kq + 3][row] = v.w;
        }
        // load B tile (16 k x 64 n), float4 per thread
        {
            int kr = tid >> 4;
            int nq = (tid & 15) * 4;
            int gn = n0 + nq;
            int gk = k0 + kr;
            float4 v = make_float4(0.f, 0.f, 0.f, 0.f);
            if (gn + 3 < N) {
                v = *(const float4*)(B + (size_t)gk * N + gn);
            } else {
                float t0 = (gn + 0 < N) ? B[(size_t)gk * N + gn + 0] : 0.f;
                float t1 = (gn + 1 < N) ? B[(size_t)gk * N + gn + 1] : 0.f;
                float t2 = (gn + 2 < N) ? B[(size_t)gk * N + gn + 2] : 0.f;
                float t3 = (gn + 3 < N) ? B[(size_t)gk * N + gn + 3] : 0.f;
                v = make_float4(t0, t1, t2, t3);
            }
            Bs[kr][nq + 0] = v.x;
            Bs[kr][nq + 1] = v.y;
            Bs[kr][nq + 2] = v.z;
            Bs[kr][nq + 3] = v.w;
        }
        __syncthreads();
        #pragma unroll
        for (int k = 0; k < BK; k++) {
            float a[4], b[4];
            #pragma unroll
            for (int i = 0; i < 4; i++) a[i] = As[k][ty * 4 + i];
            #pragma unroll
            for (int j = 0; j < 4; j++) b[j] = Bs[k][tx * 4 + j];
            #pragma unroll
            for (int i = 0; i < 4; i++)
                #pragma unroll
                for (int j = 0; j < 4; j++)
                    acc[i][j] += a[i] * b[j];
        }
        __syncthreads();
    }
    #pragma unroll
    for (int i = 0; i < 4; i++) {
        int gm = m0 + ty * 4 + i;
        if (gm >= M) continue;
        #pragma unroll
        for (int j = 0; j < 4; j++) {
            int gn = n0 + tx * 4 + j;
            if (gn >= N) continue;
            float v = acc[i][j];
            if (bias) v += bias[gn];
            if (doRelu) v = fmaxf(v, 0.f);
            C[(size_t)gm * N + gn] = v;
        }
    }
}

// Build combined GRU weight matrix Wg [192 x 384]:
// cols 0..191: r/z sums (wih stacked over whh, transposed), 192..287: i_n (wih only),
// 288..383: h_n (whh only)
__global__ void wgbuild_k(const float* __restrict__ wih, const float* __restrict__ whh,
                          float* __restrict__ Wg)
{
    int idx = blockIdx.x * 256 + threadIdx.x;
    if (idx >= 192 * 384) return;
    int k = idx / 384, j = idx % 384;
    float v;
    if (j < 192) {
        v = (k < 96) ? wih[j * 96 + k] : whh[j * 96 + (k - 96)];
    } else if (j < 288) {
        v = (k < 96) ? wih[j * 96 + k] : 0.f;
    } else {
        int t = j - 96;
        v = (k < 96) ? 0.f : whh[t * 96 + (k - 96)];
    }
    Wg[idx] = v;
}

__global__ void pad_k(const float* __restrict__ x, float* __restrict__ h)
{
    int idx = blockIdx.x * 256 + threadIdx.x;
    if (idx >= NN_ * HH) return;
    int n = idx / HH, j = idx % HH;
    h[idx] = (j < 32) ? x[n * 32 + j] : 0.f;
}

__global__ void scatter_k(const float* __restrict__ m, const int* __restrict__ ei,
                          float* __restrict__ agg)
{
    int idx = blockIdx.x * 256 + threadIdx.x;
    if (idx >= EE_ * 24) return;
    int e = idx / 24;
    int q = (idx % 24) * 4;
    int s = ei[e];
    int d = ei[EE_ + e];
    const float4 v = *(const float4*)(m + (size_t)s * HH + q);
    float* a = agg + (size_t)d * HH + q;
    atomicAdd(a + 0, v.x);
    atomicAdd(a + 1, v.y);
    atomicAdd(a + 2, v.z);
    atomicAdd(a + 3, v.w);
}

__global__ void gru_combine_k(const float* __restrict__ G2, float* __restrict__ h,
                              const float* __restrict__ bih, const float* __restrict__ bhh,
                              int n0, int rows)
{
    int idx = blockIdx.x * 256 + threadIdx.x;
    if (idx >= rows * HH) return;
    int r_ = idx / HH;
    int j  = idx % HH;
    const float* g = G2 + (size_t)r_ * 384;
    float rg = sigmoidf_(g[j]       + bih[j]       + bhh[j]);
    float zg = sigmoidf_(g[96 + j]  + bih[96 + j]  + bhh[96 + j]);
    float nn = tanhf(g[192 + j] + bih[192 + j] + rg * (g[288 + j] + bhh[192 + j]));
    size_t hi = (size_t)(n0 + r_) * HH + j;
    float hv = h[hi];
    h[hi] = (1.f - zg) * nn + zg * hv;
}

__global__ void pool_k(const float* __restrict__ h, const int* __restrict__ batch,
                       float* __restrict__ gsum)
{
    int idx = blockIdx.x * 256 + threadIdx.x;
    if (idx >= NN_ * 24) return;
    int n = idx / 24;
    int q = (idx % 24) * 4;
    int b = batch[n];
    const float4 v = *(const float4*)(h + (size_t)n * HH + q);
    float* a = gsum + (size_t)b * HH + q;
    atomicAdd(a + 0, fmaxf(v.x, 0.f));
    atomicAdd(a + 1, fmaxf(v.y, 0.f));
    atomicAdd(a + 2, fmaxf(v.z, 0.f));
    atomicAdd(a + 3, fmaxf(v.w, 0.f));
}

__global__ void cnt_k(const int* __restrict__ batch, float* __restrict__ cnt)
{
    int idx = blockIdx.x * 256 + threadIdx.x;
    if (idx >= NN_) return;
    atomicAdd(&cnt[batch[idx]], 1.f);
}

__global__ void pool_fin_k(const float* __restrict__ gsum, const float* __restrict__ cnt,
                           float* __restrict__ g)
{
    int idx = blockIdx.x * 256 + threadIdx.x;
    if (idx >= BB * HH) return;
    int b = idx / HH;
    g[idx] = gsum[idx] / fmaxf(cnt[b], 1.f);
}

__global__ void feat_k(const float* __restrict__ g1, const float* __restrict__ g2,
                       const float* __restrict__ g3, float* __restrict__ feat)
{
    int idx = blockIdx.x * 256 + threadIdx.x;
    if (idx >= BB * HH) return;
    int b = idx / HH, j = idx % HH;
    float a = g1[idx], bb = g2[idx], c = g3[idx];
    float* f = feat + (size_t)b * 384;
    f[j]        = a;
    f[96 + j]   = bb;
    f[192 + j]  = c;
    f[288 + j]  = a * bb * c;
}

__global__ void fc3_k(const float* __restrict__ t2, const float* __restrict__ w,
                      const float* __restrict__ b, float* __restrict__ out)
{
    int bidx = blockIdx.x * 256 + threadIdx.x;
    if (bidx >= BB) return;
    float a0 = b[0], a1 = b[1], a2 = b[2];
    const float* row = t2 + (size_t)bidx * 384;
    for (int k = 0; k < 384; k++) {
        float x = row[k];
        a0 += x * w[k * 3 + 0];
        a1 += x * w[k * 3 + 1];
        a2 += x * w[k * 3 + 2];
    }
    out[bidx * 3 + 0] = a0;
    out[bidx * 3 + 1] = a1;
    out[bidx * 3 + 2] = a2;
}

extern "C" void kernel_launch(void* const* d_in, const int* in_sizes, int n_in,
                              void* d_out, int out_size, void* d_ws, size_t ws_size,
                              hipStream_t stream)
{
    float* ws  = (float*)d_ws;
    float* h   = ws;                         // 19,200,000 floats
    float* m   = h   + (size_t)NN_ * HH;     // 19,200,000 (also reused as G2 chunk)
    float* agg = m   + (size_t)NN_ * HH;     // 19,200,000
    float* Wg  = agg + (size_t)NN_ * HH;     // 73,728
    float* g3  = Wg  + 192 * 384;            // 3 * 393,216
    float* gsum= g3  + 3 * (size_t)BB * HH;  // 393,216
    float* cnt = gsum + (size_t)BB * HH;     // 4,096
    // MLP temps alias the h region (h is dead by then)
    float* feat = h;                         // 1,572,864
    float* t1   = h + 2 * 1024 * 1024;       // 6,291,456
    float* t2   = h + 9 * 1024 * 1024;       // 1,572,864
    float* G2   = m;                         // CHUNK*384 = 19,200,000 exactly fits

    for (int c = 0; c < 3; c++) {
        const float* x   = (const float*)d_in[c * 8 + 0];
        const int*   ei  = (const int*)  d_in[c * 8 + 1];
        const int*   bat = (const int*)  d_in[c * 8 + 2];
        const float* W   = (const float*)d_in[c * 8 + 3];
        const float* wih = (const float*)d_in[c * 8 + 4];
        const float* whh = (const float*)d_in[c * 8 + 5];
        const float* bih = (const float*)d_in[c * 8 + 6];
        const float* bhh = (const float*)d_in[c * 8 + 7];

        wgbuild_k<<<cdiv(192 * 384, 256), 256, 0, stream>>>(wih, whh, Wg);
        pad_k<<<cdiv(NN_ * HH, 256), 256, 0, stream>>>(x, h);

        for (int l = 0; l < LL; l++) {
            // m = h @ W[l]
            gemm_k<<<dim3(cdiv(HH, BN), cdiv(NN_, BM)), 256, 0, stream>>>(
                h, h, HH, W + (size_t)l * HH * HH, nullptr, m, NN_, HH, HH, 0);
            hipMemsetAsync(agg, 0, (size_t)NN_ * HH * sizeof(float), stream);
            scatter_k<<<cdiv(EE_ * 24, 256), 256, 0, stream>>>(m, ei, agg);
            // GRU: G2 = [agg | h] @ Wg, then elementwise combine (chunked over nodes)
            for (int ch = 0; ch < NN_ / CHUNK; ch++) {
                int n0 = ch * CHUNK;
                gemm_k<<<dim3(cdiv(384, BN), cdiv(CHUNK, BM)), 256, 0, stream>>>(
                    agg + (size_t)n0 * HH, h + (size_t)n0 * HH, HH,
                    Wg, nullptr, G2, CHUNK, 384, 192, 0);
                gru_combine_k<<<cdiv(CHUNK * HH, 256), 256, 0, stream>>>(
                    G2, h, bih, bhh, n0, CHUNK);
            }
        }

        hipMemsetAsync(gsum, 0, (size_t)BB * HH * sizeof(float), stream);
        hipMemsetAsync(cnt, 0, (size_t)BB * sizeof(float), stream);
        pool_k<<<cdiv(NN_ * 24, 256), 256, 0, stream>>>(h, bat, gsum);
        cnt_k<<<cdiv(NN_, 256), 256, 0, stream>>>(bat, cnt);
        pool_fin_k<<<cdiv(BB * HH, 256), 256, 0, stream>>>(gsum, cnt, g3 + (size_t)c * BB * HH);
    }

    const float* fc1_w = (const float*)d_in[24];
    const float* fc1_b = (const float*)d_in[25];
    const float* fc2_w = (const float*)d_in[26];
    const float* fc2_b = (const float*)d_in[27];
    const float* fc3_w = (const float*)d_in[28];
    const float* fc3_b = (const float*)d_in[29];

    feat_k<<<cdiv(BB * HH, 256), 256, 0, stream>>>(
        g3, g3 + (size_t)BB * HH, g3 + 2 * (size_t)BB * HH, feat);
    gemm_k<<<dim3(cdiv(1536, BN), cdiv(BB, BM)), 256, 0, stream>>>(
        feat, feat, 384, fc1_w, fc1_b, t1, BB, 1536, 384, 1);
    gemm_k<<<dim3(cdiv(384, BN), cdiv(BB, BM)), 256, 0, stream>>>(
        t1, t1, 1536, fc2_w, fc2_b, t2, BB, 384, 1536, 1);
    fc3_k<<<cdiv(BB, 256), 256, 0, stream>>>(t2, fc3_w, fc3_b, (float*)d_out);
}

// Round 3
// 13937.953 us; speedup vs baseline: 1.5396x; 1.5396x over previous
//
#include <hip/hip_runtime.h>
#include <math.h>

#define NN_ 200000
#define EE_ 400000
#define HH  96
#define LL  6
#define BB  4096

typedef short s8v __attribute__((ext_vector_type(8)));
typedef float f4v __attribute__((ext_vector_type(4)));

static inline int cdiv(int a, int b) { return (a + b - 1) / b; }

__device__ __forceinline__ float sigmoidf_(float x) { return 1.0f / (1.0f + __expf(-x)); }
__device__ __forceinline__ float tanhf_(float x) { return 1.0f - 2.0f / (__expf(2.0f * x) + 1.0f); }
__device__ __forceinline__ unsigned short f2bf(float x) {
    unsigned u = __float_as_uint(x);
    unsigned r = u + 0x7FFF + ((u >> 16) & 1);   // RNE
    return (unsigned short)(r >> 16);
}
// load 8 consecutive fp32 and convert to a bf16x8 MFMA fragment (in-register)
__device__ __forceinline__ s8v load_bf8(const float* __restrict__ p) {
    float4 v0 = *(const float4*)p;
    float4 v1 = *(const float4*)(p + 4);
    s8v r;
    r[0] = (short)f2bf(v0.x); r[1] = (short)f2bf(v0.y);
    r[2] = (short)f2bf(v0.z); r[3] = (short)f2bf(v0.w);
    r[4] = (short)f2bf(v1.x); r[5] = (short)f2bf(v1.y);
    r[6] = (short)f2bf(v1.z); r[7] = (short)f2bf(v1.w);
    return r;
}

// ---------------------------------------------------------------------------
// fp32 tiled GEMM (MLP head): C[M,N] = A[M,K] @ B[K,N] (+bias, +relu)
// ---------------------------------------------------------------------------
#define BM 64
#define BN 64
#define BK 16
__global__ __launch_bounds__(256) void gemm_k(
    const float* __restrict__ A0, const float* __restrict__ B,
    const float* __restrict__ bias, float* __restrict__ C,
    int M, int N, int K, int doRelu)
{
    __shared__ float As[BK][BM];
    __shared__ float Bs[BK][BN];
    int tid = threadIdx.x;
    int m0 = blockIdx.y * BM;
    int n0 = blockIdx.x * BN;
    int tx = tid & 15;
    int ty = tid >> 4;
    float acc[4][4] = {};

    for (int k0 = 0; k0 < K; k0 += BK) {
        {
            int row = tid >> 2;
            int kq  = (tid & 3) * 4;
            int gm  = m0 + row;
            int gk  = k0 + kq;
            float4 v = make_float4(0.f, 0.f, 0.f, 0.f);
            if (gm < M) v = *(const float4*)(A0 + (size_t)gm * K + gk);
            As[kq + 0][row] = v.x; As[kq + 1][row] = v.y;
            As[kq + 2][row] = v.z; As[kq + 3][row] = v.w;
        }
        {
            int kr = tid >> 4;
            int nq = (tid & 15) * 4;
            int gn = n0 + nq;
            int gk = k0 + kr;
            float4 v = make_float4(0.f, 0.f, 0.f, 0.f);
            if (gn + 3 < N) v = *(const float4*)(B + (size_t)gk * N + gn);
            Bs[kr][nq + 0] = v.x; Bs[kr][nq + 1] = v.y;
            Bs[kr][nq + 2] = v.z; Bs[kr][nq + 3] = v.w;
        }
        __syncthreads();
        #pragma unroll
        for (int k = 0; k < BK; k++) {
            float a[4], b[4];
            #pragma unroll
            for (int i = 0; i < 4; i++) a[i] = As[k][ty * 4 + i];
            #pragma unroll
            for (int j = 0; j < 4; j++) b[j] = Bs[k][tx * 4 + j];
            #pragma unroll
            for (int i = 0; i < 4; i++)
                #pragma unroll
                for (int j = 0; j < 4; j++)
                    acc[i][j] += a[i] * b[j];
        }
        __syncthreads();
    }
    #pragma unroll
    for (int i = 0; i < 4; i++) {
        int gm = m0 + ty * 4 + i;
        if (gm >= M) continue;
        #pragma unroll
        for (int j = 0; j < 4; j++) {
            int gn = n0 + tx * 4 + j;
            if (gn >= N) continue;
            float v = acc[i][j];
            if (bias) v += bias[gn];
            if (doRelu) v = fmaxf(v, 0.f);
            C[(size_t)gm * N + gn] = v;
        }
    }
}

// ---------------------------------------------------------------------------
// Weight packing into MFMA B-fragment order (bf16).
// idx = ((ks*Ncols + n)*4 + quad)*8 + j  holds  B[k=ks*32+quad*8+j][n]
// ---------------------------------------------------------------------------
__global__ void packWp_k(const float* __restrict__ W, unsigned short* __restrict__ Wp)
{
    int idx = blockIdx.x * 256 + threadIdx.x;
    if (idx >= LL * 3 * 96 * 32) return;
    int j = idx & 7;
    int q = (idx >> 3) & 3;
    int rest = idx >> 5;
    int n = rest % 96;
    int rest2 = rest / 96;
    int ks = rest2 % 3;
    int l = rest2 / 3;
    int k = ks * 32 + q * 8 + j;
    Wp[idx] = f2bf(W[(size_t)l * 96 * 96 + (size_t)k * 96 + n]);
}

// Wg[k][n]: k<96 from wih (agg side), k>=96 from whh (h side).
// n in [0,192): r/z sums; [192,288): i_n (wih only); [288,384): h_n (whh only)
__global__ void packWgp_k(const float* __restrict__ wih, const float* __restrict__ whh,
                          unsigned short* __restrict__ Wgp)
{
    int idx = blockIdx.x * 256 + threadIdx.x;
    if (idx >= 6 * 384 * 32) return;
    int j = idx & 7;
    int q = (idx >> 3) & 3;
    int rest = idx >> 5;
    int n = rest % 384;
    int ks = rest / 384;
    int k = ks * 32 + q * 8 + j;
    float v;
    if (n < 192) {
        v = (k < 96) ? wih[(size_t)n * 96 + k] : whh[(size_t)n * 96 + (k - 96)];
    } else if (n < 288) {
        int jj = n - 192;
        v = (k < 96) ? wih[(size_t)(192 + jj) * 96 + k] : 0.f;
    } else {
        int jj = n - 288;
        v = (k < 96) ? 0.f : whh[(size_t)(192 + jj) * 96 + (k - 96)];
    }
    Wgp[idx] = f2bf(v);
}

__global__ void pad_k(const float* __restrict__ x, float* __restrict__ h)
{
    int idx = blockIdx.x * 256 + threadIdx.x;
    if (idx >= NN_ * HH) return;
    int n = idx / HH, j = idx % HH;
    h[idx] = (j < 32) ? x[n * 32 + j] : 0.f;
}

// ---------------------------------------------------------------------------
// m = bf16(h) @ W[l]  (bf16 MFMA, fp32 out). Block = 64 rows, 4 waves x 16 rows.
// A-frags loaded fp32 and converted in-register; B-frags direct 16B loads.
// ---------------------------------------------------------------------------
__global__ __launch_bounds__(256) void gemm1_mfma(
    const float* __restrict__ h,
    const unsigned short* __restrict__ Wp,   // this layer's pack: [3][96][4][8]
    float* __restrict__ m)
{
    int wave = threadIdx.x >> 6;
    int lane = threadIdx.x & 63;
    int quad = lane >> 4;
    int lc   = lane & 15;
    int rowA = blockIdx.x * 64 + wave * 16 + lc;

    f4v acc[6] = {};
    #pragma unroll
    for (int ks = 0; ks < 3; ks++) {
        s8v a = load_bf8(h + (size_t)rowA * 96 + ks * 32 + quad * 8);
        #pragma unroll
        for (int t = 0; t < 6; t++) {
            s8v b = *(const s8v*)(Wp + ((size_t)(ks * 96 + t * 16 + lc) * 4 + quad) * 8);
            acc[t] = __builtin_amdgcn_mfma_f32_16x16x32_bf16(a, b, acc[t], 0, 0, 0);
        }
    }
    int rowD = blockIdx.x * 64 + wave * 16 + quad * 4;
    #pragma unroll
    for (int t = 0; t < 6; t++) {
        #pragma unroll
        for (int r = 0; r < 4; r++) {
            m[(size_t)(rowD + r) * 96 + t * 16 + lc] = acc[t][r];
        }
    }
}

__global__ void scatter_k(const float* __restrict__ m, const int* __restrict__ ei,
                          float* __restrict__ agg)
{
    int idx = blockIdx.x * 256 + threadIdx.x;
    if (idx >= EE_ * 24) return;
    int e = idx / 24;
    int q = (idx % 24) * 4;
    int s = ei[e];
    int d = ei[EE_ + e];
    const float4 v = *(const float4*)(m + (size_t)s * HH + q);
    float* a = agg + (size_t)d * HH + q;
    atomicAdd(a + 0, v.x);
    atomicAdd(a + 1, v.y);
    atomicAdd(a + 2, v.z);
    atomicAdd(a + 3, v.w);
}

// ---------------------------------------------------------------------------
// Fused GRU: G = bf16([agg | h]) @ Wg (192x384 bf16 MFMA); GRUCell applied
// lane-locally in the epilogue (cols j, 96+j, 192+j, 288+j sit in the same
// lane/reg of acc tiles t, t+6, t+12, t+18 since 96 = 6*16). Updates h in
// place; each wave touches only its own 16 rows -> hazard-free.
// ---------------------------------------------------------------------------
__global__ __launch_bounds__(256) void gru_mfma(
    const float* __restrict__ agg,
    const unsigned short* __restrict__ Wgp,
    const float* __restrict__ bih, const float* __restrict__ bhh,
    float* __restrict__ h)
{
    int wave = threadIdx.x >> 6;
    int lane = threadIdx.x & 63;
    int quad = lane >> 4;
    int lc   = lane & 15;
    int rowA = blockIdx.x * 64 + wave * 16 + lc;

    f4v acc[24] = {};
    #pragma unroll
    for (int ks = 0; ks < 3; ks++) {
        s8v a = load_bf8(agg + (size_t)rowA * 96 + ks * 32 + quad * 8);
        #pragma unroll
        for (int t = 0; t < 24; t++) {
            s8v b = *(const s8v*)(Wgp + ((size_t)(ks * 384 + t * 16 + lc) * 4 + quad) * 8);
            acc[t] = __builtin_amdgcn_mfma_f32_16x16x32_bf16(a, b, acc[t], 0, 0, 0);
        }
    }
    #pragma unroll
    for (int ks = 0; ks < 3; ks++) {
        s8v a = load_bf8(h + (size_t)rowA * 96 + ks * 32 + quad * 8);
        #pragma unroll
        for (int t = 0; t < 24; t++) {
            s8v b = *(const s8v*)(Wgp + ((size_t)((ks + 3) * 384 + t * 16 + lc) * 4 + quad) * 8);
            acc[t] = __builtin_amdgcn_mfma_f32_16x16x32_bf16(a, b, acc[t], 0, 0, 0);
        }
    }
    int rowD = blockIdx.x * 64 + wave * 16 + quad * 4;
    #pragma unroll
    for (int t = 0; t < 6; t++) {
        int j = t * 16 + lc;
        float bi_r = bih[j],       bh_r = bhh[j];
        float bi_z = bih[96 + j],  bh_z = bhh[96 + j];
        float bi_n = bih[192 + j], bh_n = bhh[192 + j];
        #pragma unroll
        for (int r = 0; r < 4; r++) {
            float rg = sigmoidf_(acc[t][r]      + bi_r + bh_r);
            float zg = sigmoidf_(acc[t + 6][r]  + bi_z + bh_z);
            float nn = tanhf_(acc[t + 12][r] + bi_n + rg * (acc[t + 18][r] + bh_n));
            size_t hi = (size_t)(rowD + r) * 96 + j;
            float hv = h[hi];
            h[hi] = (1.f - zg) * nn + zg * hv;
        }
    }
}

__global__ void pool_k(const float* __restrict__ h, const int* __restrict__ batch,
                       float* __restrict__ gsum)
{
    int idx = blockIdx.x * 256 + threadIdx.x;
    if (idx >= NN_ * 24) return;
    int n = idx / 24;
    int q = (idx % 24) * 4;
    int b = batch[n];
    const float4 v = *(const float4*)(h + (size_t)n * HH + q);
    float* a = gsum + (size_t)b * HH + q;
    atomicAdd(a + 0, fmaxf(v.x, 0.f));
    atomicAdd(a + 1, fmaxf(v.y, 0.f));
    atomicAdd(a + 2, fmaxf(v.z, 0.f));
    atomicAdd(a + 3, fmaxf(v.w, 0.f));
}

__global__ void cnt_k(const int* __restrict__ batch, float* __restrict__ cnt)
{
    int idx = blockIdx.x * 256 + threadIdx.x;
    if (idx >= NN_) return;
    atomicAdd(&cnt[batch[idx]], 1.f);
}

__global__ void pool_fin_k(const float* __restrict__ gsum, const float* __restrict__ cnt,
                           float* __restrict__ g)
{
    int idx = blockIdx.x * 256 + threadIdx.x;
    if (idx >= BB * HH) return;
    int b = idx / HH;
    g[idx] = gsum[idx] / fmaxf(cnt[b], 1.f);
}

__global__ void feat_k(const float* __restrict__ g1, const float* __restrict__ g2,
                       const float* __restrict__ g3, float* __restrict__ feat)
{
    int idx = blockIdx.x * 256 + threadIdx.x;
    if (idx >= BB * HH) return;
    int b = idx / HH, j = idx % HH;
    float a = g1[idx], bb = g2[idx], c = g3[idx];
    float* f = feat + (size_t)b * 384;
    f[j]       = a;
    f[96 + j]  = bb;
    f[192 + j] = c;
    f[288 + j] = a * bb * c;
}

__global__ void fc3_k(const float* __restrict__ t2, const float* __restrict__ w,
                      const float* __restrict__ b, float* __restrict__ out)
{
    int bidx = blockIdx.x * 256 + threadIdx.x;
    if (bidx >= BB) return;
    float a0 = b[0], a1 = b[1], a2 = b[2];
    const float* row = t2 + (size_t)bidx * 384;
    for (int k = 0; k < 384; k++) {
        float x = row[k];
        a0 += x * w[k * 3 + 0];
        a1 += x * w[k * 3 + 1];
        a2 += x * w[k * 3 + 2];
    }
    out[bidx * 3 + 0] = a0;
    out[bidx * 3 + 1] = a1;
    out[bidx * 3 + 2] = a2;
}

extern "C" void kernel_launch(void* const* d_in, const int* in_sizes, int n_in,
                              void* d_out, int out_size, void* d_ws, size_t ws_size,
                              hipStream_t stream)
{
    // Workspace layout (floats). Total = 59,241,472 f = 236.97 MB
    // (Round-1's 237.0 MB footprint was proven safe; Round-2's 275.6 MB crashed.)
    float* ws   = (float*)d_ws;
    float* h    = ws;                               // 19,200,000
    float* m    = h + (size_t)NN_ * HH;             // 19,200,000
    float* agg  = m + (size_t)NN_ * HH;             // 19,200,000
    float* wpF  = agg + (size_t)NN_ * HH;           // 27,648 f (55,296 bf16)
    float* wgpF = wpF + 27648;                      // 36,864 f (73,728 bf16)
    float* g3   = wgpF + 36864;                     // 3 * 393,216
    float* gsum = g3 + 3 * (size_t)BB * HH;         // 393,216
    float* cnt  = gsum + (size_t)BB * HH;           // 4,096

    unsigned short* Wp  = (unsigned short*)wpF;
    unsigned short* Wgp = (unsigned short*)wgpF;

    // MLP temps alias h (dead after pooling)
    float* feat = h;
    float* t1   = h + 2 * 1024 * 1024;
    float* t2   = h + 9 * 1024 * 1024;

    for (int c = 0; c < 3; c++) {
        const float* x   = (const float*)d_in[c * 8 + 0];
        const int*   ei  = (const int*)  d_in[c * 8 + 1];
        const int*   bat = (const int*)  d_in[c * 8 + 2];
        const float* W   = (const float*)d_in[c * 8 + 3];
        const float* wih = (const float*)d_in[c * 8 + 4];
        const float* whh = (const float*)d_in[c * 8 + 5];
        const float* bih = (const float*)d_in[c * 8 + 6];
        const float* bhh = (const float*)d_in[c * 8 + 7];

        packWp_k<<<cdiv(LL * 3 * 96 * 32, 256), 256, 0, stream>>>(W, Wp);
        packWgp_k<<<cdiv(6 * 384 * 32, 256), 256, 0, stream>>>(wih, whh, Wgp);
        pad_k<<<cdiv(NN_ * HH, 256), 256, 0, stream>>>(x, h);

        for (int l = 0; l < LL; l++) {
            gemm1_mfma<<<NN_ / 64, 256, 0, stream>>>(h, Wp + (size_t)l * 3 * 96 * 32, m);
            hipMemsetAsync(agg, 0, (size_t)NN_ * HH * sizeof(float), stream);
            scatter_k<<<cdiv(EE_ * 24, 256), 256, 0, stream>>>(m, ei, agg);
            gru_mfma<<<NN_ / 64, 256, 0, stream>>>(agg, Wgp, bih, bhh, h);
        }

        hipMemsetAsync(gsum, 0, (size_t)BB * HH * sizeof(float), stream);
        hipMemsetAsync(cnt, 0, (size_t)BB * sizeof(float), stream);
        pool_k<<<cdiv(NN_ * 24, 256), 256, 0, stream>>>(h, bat, gsum);
        cnt_k<<<cdiv(NN_, 256), 256, 0, stream>>>(bat, cnt);
        pool_fin_k<<<cdiv(BB * HH, 256), 256, 0, stream>>>(gsum, cnt, g3 + (size_t)c * BB * HH);
    }

    const float* fc1_w = (const float*)d_in[24];
    const float* fc1_b = (const float*)d_in[25];
    const float* fc2_w = (const float*)d_in[26];
    const float* fc2_b = (const float*)d_in[27];
    const float* fc3_w = (const float*)d_in[28];
    const float* fc3_b = (const float*)d_in[29];

    feat_k<<<cdiv(BB * HH, 256), 256, 0, stream>>>(
        g3, g3 + (size_t)BB * HH, g3 + 2 * (size_t)BB * HH, feat);
    gemm_k<<<dim3(cdiv(1536, BN), cdiv(BB, BM)), 256, 0, stream>>>(
        feat, fc1_w, fc1_b, t1, BB, 1536, 384, 1);
    gemm_k<<<dim3(cdiv(384, BN), cdiv(BB, BM)), 256, 0, stream>>>(
        t1, fc2_w, fc2_b, t2, BB, 384, 1536, 1);
    fc3_k<<<cdiv(BB, 256), 256, 0, stream>>>(t2, fc3_w, fc3_b, (float*)d_out);
}

// Round 4
// 6085.782 us; speedup vs baseline: 3.5260x; 2.2902x over previous
//
#include <hip/hip_runtime.h>
#include <math.h>

#define NN_ 200000
#define EE_ 400000
#define HH  96
#define LL  6
#define BB  4096
#define SCAN_B 1024
#define NB_SCAN 196   // cdiv(200000, 1024)

typedef short s8v __attribute__((ext_vector_type(8)));
typedef float f4v __attribute__((ext_vector_type(4)));

static inline int cdiv(int a, int b) { return (a + b - 1) / b; }

__device__ __forceinline__ float sigmoidf_(float x) { return 1.0f / (1.0f + __expf(-x)); }
__device__ __forceinline__ float tanhf_(float x) { return 1.0f - 2.0f / (__expf(2.0f * x) + 1.0f); }
__device__ __forceinline__ unsigned short f2bf(float x) {
    unsigned u = __float_as_uint(x);
    unsigned r = u + 0x7FFF + ((u >> 16) & 1);   // RNE
    return (unsigned short)(r >> 16);
}
__device__ __forceinline__ float bf2f(unsigned short u) {
    return __uint_as_float(((unsigned)u) << 16);
}
// load 8 consecutive fp32 and convert to a bf16x8 MFMA fragment (in-register)
__device__ __forceinline__ s8v load_bf8(const float* __restrict__ p) {
    float4 v0 = *(const float4*)p;
    float4 v1 = *(const float4*)(p + 4);
    s8v r;
    r[0] = (short)f2bf(v0.x); r[1] = (short)f2bf(v0.y);
    r[2] = (short)f2bf(v0.z); r[3] = (short)f2bf(v0.w);
    r[4] = (short)f2bf(v1.x); r[5] = (short)f2bf(v1.y);
    r[6] = (short)f2bf(v1.z); r[7] = (short)f2bf(v1.w);
    return r;
}

// ---------------------------------------------------------------------------
// fp32 tiled GEMM (MLP head): C[M,N] = A[M,K] @ B[K,N] (+bias, +relu)
// ---------------------------------------------------------------------------
#define BM 64
#define BN 64
#define BK 16
__global__ __launch_bounds__(256) void gemm_k(
    const float* __restrict__ A0, const float* __restrict__ B,
    const float* __restrict__ bias, float* __restrict__ C,
    int M, int N, int K, int doRelu)
{
    __shared__ float As[BK][BM];
    __shared__ float Bs[BK][BN];
    int tid = threadIdx.x;
    int m0 = blockIdx.y * BM;
    int n0 = blockIdx.x * BN;
    int tx = tid & 15;
    int ty = tid >> 4;
    float acc[4][4] = {};

    for (int k0 = 0; k0 < K; k0 += BK) {
        {
            int row = tid >> 2;
            int kq  = (tid & 3) * 4;
            int gm  = m0 + row;
            int gk  = k0 + kq;
            float4 v = make_float4(0.f, 0.f, 0.f, 0.f);
            if (gm < M) v = *(const float4*)(A0 + (size_t)gm * K + gk);
            As[kq + 0][row] = v.x; As[kq + 1][row] = v.y;
            As[kq + 2][row] = v.z; As[kq + 3][row] = v.w;
        }
        {
            int kr = tid >> 4;
            int nq = (tid & 15) * 4;
            int gn = n0 + nq;
            int gk = k0 + kr;
            float4 v = make_float4(0.f, 0.f, 0.f, 0.f);
            if (gn + 3 < N) v = *(const float4*)(B + (size_t)gk * N + gn);
            Bs[kr][nq + 0] = v.x; Bs[kr][nq + 1] = v.y;
            Bs[kr][nq + 2] = v.z; Bs[kr][nq + 3] = v.w;
        }
        __syncthreads();
        #pragma unroll
        for (int k = 0; k < BK; k++) {
            float a[4], b[4];
            #pragma unroll
            for (int i = 0; i < 4; i++) a[i] = As[k][ty * 4 + i];
            #pragma unroll
            for (int j = 0; j < 4; j++) b[j] = Bs[k][tx * 4 + j];
            #pragma unroll
            for (int i = 0; i < 4; i++)
                #pragma unroll
                for (int j = 0; j < 4; j++)
                    acc[i][j] += a[i] * b[j];
        }
        __syncthreads();
    }
    #pragma unroll
    for (int i = 0; i < 4; i++) {
        int gm = m0 + ty * 4 + i;
        if (gm >= M) continue;
        #pragma unroll
        for (int j = 0; j < 4; j++) {
            int gn = n0 + tx * 4 + j;
            if (gn >= N) continue;
            float v = acc[i][j];
            if (bias) v += bias[gn];
            if (doRelu) v = fmaxf(v, 0.f);
            C[(size_t)gm * N + gn] = v;
        }
    }
}

// ---------------------------------------------------------------------------
// Weight packing into MFMA B-fragment order (bf16).
// idx = ((ks*Ncols + n)*4 + quad)*8 + j  holds  B[k=ks*32+quad*8+j][n]
// ---------------------------------------------------------------------------
__global__ void packWp_k(const float* __restrict__ W, unsigned short* __restrict__ Wp)
{
    int idx = blockIdx.x * 256 + threadIdx.x;
    if (idx >= LL * 3 * 96 * 32) return;
    int j = idx & 7;
    int q = (idx >> 3) & 3;
    int rest = idx >> 5;
    int n = rest % 96;
    int rest2 = rest / 96;
    int ks = rest2 % 3;
    int l = rest2 / 3;
    int k = ks * 32 + q * 8 + j;
    Wp[idx] = f2bf(W[(size_t)l * 96 * 96 + (size_t)k * 96 + n]);
}

// Wg[k][n]: k<96 from wih (agg side), k>=96 from whh (h side).
// n in [0,192): r/z sums; [192,288): i_n (wih only); [288,384): h_n (whh only)
__global__ void packWgp_k(const float* __restrict__ wih, const float* __restrict__ whh,
                          unsigned short* __restrict__ Wgp)
{
    int idx = blockIdx.x * 256 + threadIdx.x;
    if (idx >= 6 * 384 * 32) return;
    int j = idx & 7;
    int q = (idx >> 3) & 3;
    int rest = idx >> 5;
    int n = rest % 384;
    int ks = rest / 384;
    int k = ks * 32 + q * 8 + j;
    float v;
    if (n < 192) {
        v = (k < 96) ? wih[(size_t)n * 96 + k] : whh[(size_t)n * 96 + (k - 96)];
    } else if (n < 288) {
        int jj = n - 192;
        v = (k < 96) ? wih[(size_t)(192 + jj) * 96 + k] : 0.f;
    } else {
        int jj = n - 288;
        v = (k < 96) ? 0.f : whh[(size_t)(192 + jj) * 96 + (k - 96)];
    }
    Wgp[idx] = f2bf(v);
}

__global__ void pad_k(const float* __restrict__ x, float* __restrict__ h)
{
    int idx = blockIdx.x * 256 + threadIdx.x;
    if (idx >= NN_ * HH) return;
    int n = idx / HH, j = idx % HH;
    h[idx] = (j < 32) ? x[n * 32 + j] : 0.f;
}

// --------------------------- CSR build (once per component) -----------------
__global__ void deg_k(const int* __restrict__ ei, int* __restrict__ deg)
{
    int e = blockIdx.x * 256 + threadIdx.x;
    if (e >= EE_) return;
    atomicAdd(&deg[ei[EE_ + e]], 1);
}

__global__ __launch_bounds__(SCAN_B) void scan1_k(
    const int* __restrict__ deg, int* __restrict__ rp, int* __restrict__ bsum)
{
    __shared__ int sh[SCAN_B];
    int i = blockIdx.x * SCAN_B + threadIdx.x;
    int v = (i < NN_) ? deg[i] : 0;
    sh[threadIdx.x] = v;
    __syncthreads();
    for (int off = 1; off < SCAN_B; off <<= 1) {
        int t = (threadIdx.x >= off) ? sh[threadIdx.x - off] : 0;
        __syncthreads();
        sh[threadIdx.x] += t;
        __syncthreads();
    }
    if (i < NN_) rp[i] = sh[threadIdx.x] - v;     // exclusive within block
    if (threadIdx.x == SCAN_B - 1) bsum[blockIdx.x] = sh[threadIdx.x];
}

__global__ __launch_bounds__(256) void scan2_k(int* __restrict__ bsum)
{
    __shared__ int sh[256];
    int v = (threadIdx.x < NB_SCAN) ? bsum[threadIdx.x] : 0;
    sh[threadIdx.x] = v;
    __syncthreads();
    for (int off = 1; off < 256; off <<= 1) {
        int t = (threadIdx.x >= off) ? sh[threadIdx.x - off] : 0;
        __syncthreads();
        sh[threadIdx.x] += t;
        __syncthreads();
    }
    if (threadIdx.x < NB_SCAN) bsum[threadIdx.x] = sh[threadIdx.x] - v;  // exclusive
}

__global__ void scan3_k(int* __restrict__ rp, const int* __restrict__ bsum,
                        int* __restrict__ cur)
{
    int i = blockIdx.x * 256 + threadIdx.x;
    if (i < NN_) {
        int r = rp[i] + bsum[i / SCAN_B];
        rp[i] = r;
        cur[i] = r;
    }
    if (i == 0) rp[NN_] = EE_;
}

__global__ void fill_k(const int* __restrict__ ei, int* __restrict__ cur,
                       int* __restrict__ srcs)
{
    int e = blockIdx.x * 256 + threadIdx.x;
    if (e >= EE_) return;
    int s = ei[e];
    int d = ei[EE_ + e];
    int pos = atomicAdd(&cur[d], 1);
    srcs[pos] = s;
}

// ---------------------------------------------------------------------------
// m_bf = bf16( bf16(h) @ W[l] )  (bf16 MFMA, fp32 acc). 64 rows/block.
// ---------------------------------------------------------------------------
__global__ __launch_bounds__(256) void gemm1_mfma(
    const float* __restrict__ h,
    const unsigned short* __restrict__ Wp,   // this layer's pack: [3][96][4][8]
    unsigned short* __restrict__ m_bf)
{
    int wave = threadIdx.x >> 6;
    int lane = threadIdx.x & 63;
    int quad = lane >> 4;
    int lc   = lane & 15;
    int rowA = blockIdx.x * 64 + wave * 16 + lc;

    f4v acc[6] = {};
    #pragma unroll
    for (int ks = 0; ks < 3; ks++) {
        s8v a = load_bf8(h + (size_t)rowA * 96 + ks * 32 + quad * 8);
        #pragma unroll
        for (int t = 0; t < 6; t++) {
            s8v b = *(const s8v*)(Wp + ((size_t)(ks * 96 + t * 16 + lc) * 4 + quad) * 8);
            acc[t] = __builtin_amdgcn_mfma_f32_16x16x32_bf16(a, b, acc[t], 0, 0, 0);
        }
    }
    int rowD = blockIdx.x * 64 + wave * 16 + quad * 4;
    #pragma unroll
    for (int t = 0; t < 6; t++) {
        #pragma unroll
        for (int r = 0; r < 4; r++) {
            m_bf[(size_t)(rowD + r) * 96 + t * 16 + lc] = f2bf(acc[t][r]);
        }
    }
}

// ---------------------------------------------------------------------------
// CSR aggregation: agg_bf[n] = bf16( sum_{e in CSR[n]} m_bf[srcs[e]] ).
// One thread per (node, 8-feature group); no atomics, coalesced writes.
// ---------------------------------------------------------------------------
__global__ void agg_csr_k(const unsigned short* __restrict__ m_bf,
                          const int* __restrict__ rp, const int* __restrict__ srcs,
                          unsigned short* __restrict__ agg_bf)
{
    int idx = blockIdx.x * 256 + threadIdx.x;
    if (idx >= NN_ * 12) return;
    int node = idx / 12;
    int g = (idx % 12) * 8;
    int e0 = rp[node], e1 = rp[node + 1];
    float s0 = 0.f, s1 = 0.f, s2 = 0.f, s3 = 0.f;
    float s4 = 0.f, s5 = 0.f, s6 = 0.f, s7 = 0.f;
    for (int e = e0; e < e1; e++) {
        int sr = srcs[e];
        uint4 u = *(const uint4*)(m_bf + (size_t)sr * 96 + g);
        s0 += bf2f((unsigned short)(u.x & 0xFFFF));
        s1 += bf2f((unsigned short)(u.x >> 16));
        s2 += bf2f((unsigned short)(u.y & 0xFFFF));
        s3 += bf2f((unsigned short)(u.y >> 16));
        s4 += bf2f((unsigned short)(u.z & 0xFFFF));
        s5 += bf2f((unsigned short)(u.z >> 16));
        s6 += bf2f((unsigned short)(u.w & 0xFFFF));
        s7 += bf2f((unsigned short)(u.w >> 16));
    }
    uint4 o;
    o.x = (unsigned)f2bf(s0) | ((unsigned)f2bf(s1) << 16);
    o.y = (unsigned)f2bf(s2) | ((unsigned)f2bf(s3) << 16);
    o.z = (unsigned)f2bf(s4) | ((unsigned)f2bf(s5) << 16);
    o.w = (unsigned)f2bf(s6) | ((unsigned)f2bf(s7) << 16);
    *(uint4*)(agg_bf + (size_t)node * 96 + g) = o;
}

// ---------------------------------------------------------------------------
// Fused GRU: G = [agg_bf | bf16(h)] @ Wg (192x384 bf16 MFMA); GRUCell applied
// lane-locally in the epilogue (cols j, 96+j, 192+j, 288+j sit in the same
// lane/reg of acc tiles t, t+6, t+12, t+18 since 96 = 6*16). Updates h in
// place; each wave touches only its own 16 rows -> hazard-free.
// ---------------------------------------------------------------------------
__global__ __launch_bounds__(256) void gru_mfma(
    const unsigned short* __restrict__ agg_bf,
    const unsigned short* __restrict__ Wgp,
    const float* __restrict__ bih, const float* __restrict__ bhh,
    float* __restrict__ h)
{
    int wave = threadIdx.x >> 6;
    int lane = threadIdx.x & 63;
    int quad = lane >> 4;
    int lc   = lane & 15;
    int rowA = blockIdx.x * 64 + wave * 16 + lc;

    f4v acc[24] = {};
    #pragma unroll
    for (int ks = 0; ks < 3; ks++) {
        s8v a = *(const s8v*)(agg_bf + (size_t)rowA * 96 + ks * 32 + quad * 8);
        #pragma unroll
        for (int t = 0; t < 24; t++) {
            s8v b = *(const s8v*)(Wgp + ((size_t)(ks * 384 + t * 16 + lc) * 4 + quad) * 8);
            acc[t] = __builtin_amdgcn_mfma_f32_16x16x32_bf16(a, b, acc[t], 0, 0, 0);
        }
    }
    #pragma unroll
    for (int ks = 0; ks < 3; ks++) {
        s8v a = load_bf8(h + (size_t)rowA * 96 + ks * 32 + quad * 8);
        #pragma unroll
        for (int t = 0; t < 24; t++) {
            s8v b = *(const s8v*)(Wgp + ((size_t)((ks + 3) * 384 + t * 16 + lc) * 4 + quad) * 8);
            acc[t] = __builtin_amdgcn_mfma_f32_16x16x32_bf16(a, b, acc[t], 0, 0, 0);
        }
    }
    int rowD = blockIdx.x * 64 + wave * 16 + quad * 4;
    #pragma unroll
    for (int t = 0; t < 6; t++) {
        int j = t * 16 + lc;
        float bi_r = bih[j],       bh_r = bhh[j];
        float bi_z = bih[96 + j],  bh_z = bhh[96 + j];
        float bi_n = bih[192 + j], bh_n = bhh[192 + j];
        #pragma unroll
        for (int r = 0; r < 4; r++) {
            float rg = sigmoidf_(acc[t][r]      + bi_r + bh_r);
            float zg = sigmoidf_(acc[t + 6][r]  + bi_z + bh_z);
            float nn = tanhf_(acc[t + 12][r] + bi_n + rg * (acc[t + 18][r] + bh_n));
            size_t hi = (size_t)(rowD + r) * 96 + j;
            float hv = h[hi];
            h[hi] = (1.f - zg) * nn + zg * hv;
        }
    }
}

__global__ void pool_k(const float* __restrict__ h, const int* __restrict__ batch,
                       float* __restrict__ gsum)
{
    int idx = blockIdx.x * 256 + threadIdx.x;
    if (idx >= NN_ * 24) return;
    int n = idx / 24;
    int q = (idx % 24) * 4;
    int b = batch[n];
    const float4 v = *(const float4*)(h + (size_t)n * HH + q);
    float* a = gsum + (size_t)b * HH + q;
    atomicAdd(a + 0, fmaxf(v.x, 0.f));
    atomicAdd(a + 1, fmaxf(v.y, 0.f));
    atomicAdd(a + 2, fmaxf(v.z, 0.f));
    atomicAdd(a + 3, fmaxf(v.w, 0.f));
}

__global__ void cnt_k(const int* __restrict__ batch, float* __restrict__ cnt)
{
    int idx = blockIdx.x * 256 + threadIdx.x;
    if (idx >= NN_) return;
    atomicAdd(&cnt[batch[idx]], 1.f);
}

__global__ void pool_fin_k(const float* __restrict__ gsum, const float* __restrict__ cnt,
                           float* __restrict__ g)
{
    int idx = blockIdx.x * 256 + threadIdx.x;
    if (idx >= BB * HH) return;
    int b = idx / HH;
    g[idx] = gsum[idx] / fmaxf(cnt[b], 1.f);
}

__global__ void feat_k(const float* __restrict__ g1, const float* __restrict__ g2,
                       const float* __restrict__ g3, float* __restrict__ feat)
{
    int idx = blockIdx.x * 256 + threadIdx.x;
    if (idx >= BB * HH) return;
    int b = idx / HH, j = idx % HH;
    float a = g1[idx], bb = g2[idx], c = g3[idx];
    float* f = feat + (size_t)b * 384;
    f[j]       = a;
    f[96 + j]  = bb;
    f[192 + j] = c;
    f[288 + j] = a * bb * c;
}

__global__ void fc3_k(const float* __restrict__ t2, const float* __restrict__ w,
                      const float* __restrict__ b, float* __restrict__ out)
{
    int bidx = blockIdx.x * 256 + threadIdx.x;
    if (bidx >= BB) return;
    float a0 = b[0], a1 = b[1], a2 = b[2];
    const float* row = t2 + (size_t)bidx * 384;
    for (int k = 0; k < 384; k++) {
        float x = row[k];
        a0 += x * w[k * 3 + 0];
        a1 += x * w[k * 3 + 1];
        a2 += x * w[k * 3 + 2];
    }
    out[bidx * 3 + 0] = a0;
    out[bidx * 3 + 1] = a1;
    out[bidx * 3 + 2] = a2;
}

extern "C" void kernel_launch(void* const* d_in, const int* in_sizes, int n_in,
                              void* d_out, int out_size, void* d_ws, size_t ws_size,
                              hipStream_t stream)
{
    // Workspace (floats). Total ~40.9M f = 163.5 MB (237 MB proven safe).
    float* ws   = (float*)d_ws;
    float* h    = ws;                               // 19,200,000
    float* mbfF = h + (size_t)NN_ * HH;             //  9,600,000 (19.2M bf16)
    float* abfF = mbfF + (size_t)NN_ * HH / 2;      //  9,600,000 (19.2M bf16)
    float* wpF  = abfF + (size_t)NN_ * HH / 2;      //     27,648
    float* wgpF = wpF + 27648;                      //     36,864
    float* g3   = wgpF + 36864;                     //  1,179,648
    float* gsum = g3 + 3 * (size_t)BB * HH;         //    393,216
    float* cnt  = gsum + (size_t)BB * HH;           //      4,096
    int*   rp   = (int*)(cnt + BB);                 //    200,064 ints
    int*   srcs = rp + 200064;                      //    400,000 ints
    int*   deg  = srcs + 400000;                    //    200,000 ints (also scan temp)
    int*   cur  = deg + 200000;                     //    200,000 ints
    int*   bsum = cur + 200000;                     //        256 ints

    unsigned short* m_bf   = (unsigned short*)mbfF;
    unsigned short* agg_bf = (unsigned short*)abfF;
    unsigned short* Wp     = (unsigned short*)wpF;
    unsigned short* Wgp    = (unsigned short*)wgpF;

    // MLP temps alias h (dead after pooling)
    float* feat = h;
    float* t1   = h + 2 * 1024 * 1024;
    float* t2   = h + 9 * 1024 * 1024;

    for (int c = 0; c < 3; c++) {
        const float* x   = (const float*)d_in[c * 8 + 0];
        const int*   ei  = (const int*)  d_in[c * 8 + 1];
        const int*   bat = (const int*)  d_in[c * 8 + 2];
        const float* W   = (const float*)d_in[c * 8 + 3];
        const float* wih = (const float*)d_in[c * 8 + 4];
        const float* whh = (const float*)d_in[c * 8 + 5];
        const float* bih = (const float*)d_in[c * 8 + 6];
        const float* bhh = (const float*)d_in[c * 8 + 7];

        // CSR build (once per component, reused for all 6 layers)
        hipMemsetAsync(deg, 0, NN_ * sizeof(int), stream);
        deg_k<<<cdiv(EE_, 256), 256, 0, stream>>>(ei, deg);
        scan1_k<<<NB_SCAN, SCAN_B, 0, stream>>>(deg, rp, bsum);
        scan2_k<<<1, 256, 0, stream>>>(bsum);
        scan3_k<<<cdiv(NN_, 256), 256, 0, stream>>>(rp, bsum, cur);
        fill_k<<<cdiv(EE_, 256), 256, 0, stream>>>(ei, cur, srcs);

        packWp_k<<<cdiv(LL * 3 * 96 * 32, 256), 256, 0, stream>>>(W, Wp);
        packWgp_k<<<cdiv(6 * 384 * 32, 256), 256, 0, stream>>>(wih, whh, Wgp);
        pad_k<<<cdiv(NN_ * HH, 256), 256, 0, stream>>>(x, h);

        for (int l = 0; l < LL; l++) {
            gemm1_mfma<<<NN_ / 64, 256, 0, stream>>>(h, Wp + (size_t)l * 3 * 96 * 32, m_bf);
            agg_csr_k<<<cdiv(NN_ * 12, 256), 256, 0, stream>>>(m_bf, rp, srcs, agg_bf);
            gru_mfma<<<NN_ / 64, 256, 0, stream>>>(agg_bf, Wgp, bih, bhh, h);
        }

        hipMemsetAsync(gsum, 0, (size_t)BB * HH * sizeof(float), stream);
        hipMemsetAsync(cnt, 0, (size_t)BB * sizeof(float), stream);
        pool_k<<<cdiv(NN_ * 24, 256), 256, 0, stream>>>(h, bat, gsum);
        cnt_k<<<cdiv(NN_, 256), 256, 0, stream>>>(bat, cnt);
        pool_fin_k<<<cdiv(BB * HH, 256), 256, 0, stream>>>(gsum, cnt, g3 + (size_t)c * BB * HH);
    }

    const float* fc1_w = (const float*)d_in[24];
    const float* fc1_b = (const float*)d_in[25];
    const float* fc2_w = (const float*)d_in[26];
    const float* fc2_b = (const float*)d_in[27];
    const float* fc3_w = (const float*)d_in[28];
    const float* fc3_b = (const float*)d_in[29];

    feat_k<<<cdiv(BB * HH, 256), 256, 0, stream>>>(
        g3, g3 + (size_t)BB * HH, g3 + 2 * (size_t)BB * HH, feat);
    gemm_k<<<dim3(cdiv(1536, BN), cdiv(BB, BM)), 256, 0, stream>>>(
        feat, fc1_w, fc1_b, t1, BB, 1536, 384, 1);
    gemm_k<<<dim3(cdiv(384, BN), cdiv(BB, BM)), 256, 0, stream>>>(
        t1, fc2_w, fc2_b, t2, BB, 384, 1536, 1);
    fc3_k<<<cdiv(BB, 256), 256, 0, stream>>>(t2, fc3_w, fc3_b, (float*)d_out);
}

// Round 6
// 5059.402 us; speedup vs baseline: 4.2413x; 1.2029x over previous
//
#include <hip/hip_runtime.h>
#include <math.h>

#define NN_ 200000
#define EE_ 400000
#define HH  96
#define LL  6
#define BB  4096
#define SCAN_B 1024
#define NB_SCAN 196   // cdiv(200000, 1024)

typedef short s8v __attribute__((ext_vector_type(8)));
typedef float f4v __attribute__((ext_vector_type(4)));

static inline int cdiv(int a, int b) { return (a + b - 1) / b; }

__device__ __forceinline__ float sigmoidf_(float x) { return 1.0f / (1.0f + __expf(-x)); }
__device__ __forceinline__ float tanhf_(float x) { return 1.0f - 2.0f / (__expf(2.0f * x) + 1.0f); }
__device__ __forceinline__ unsigned short f2bf(float x) {
    unsigned u = __float_as_uint(x);
    unsigned r = u + 0x7FFF + ((u >> 16) & 1);   // RNE
    return (unsigned short)(r >> 16);
}
__device__ __forceinline__ float bf2f(unsigned short u) {
    return __uint_as_float(((unsigned)u) << 16);
}
// load 8 consecutive fp32 and convert to a bf16x8 MFMA fragment (in-register)
__device__ __forceinline__ s8v load_bf8(const float* __restrict__ p) {
    float4 v0 = *(const float4*)p;
    float4 v1 = *(const float4*)(p + 4);
    s8v r;
    r[0] = (short)f2bf(v0.x); r[1] = (short)f2bf(v0.y);
    r[2] = (short)f2bf(v0.z); r[3] = (short)f2bf(v0.w);
    r[4] = (short)f2bf(v1.x); r[5] = (short)f2bf(v1.y);
    r[6] = (short)f2bf(v1.z); r[7] = (short)f2bf(v1.w);
    return r;
}

// ---------------------------------------------------------------------------
// Weight packing into MFMA B-fragment order (bf16).
// Bp[((k>>5)*N + n)*32 + ((k>>3)&3)*8 + (k&7)] = bf16(B[k*N + n])
// so lane lc of col-tile t reads 8 consecutive bf16 at ((ks*N + t*16+lc)*4 + quad)*8
// ---------------------------------------------------------------------------
__global__ void packB_k(const float* __restrict__ B, unsigned short* __restrict__ Bp,
                        int K, int N)
{
    int idx = blockIdx.x * 256 + threadIdx.x;
    if (idx >= K * N) return;
    int k = idx / N, n = idx % N;
    Bp[(((size_t)(k >> 5) * N + n) * 4 + ((k >> 3) & 3)) * 8 + (k & 7)] = f2bf(B[idx]);
}

__global__ void packWp_k(const float* __restrict__ W, unsigned short* __restrict__ Wp)
{
    int idx = blockIdx.x * 256 + threadIdx.x;
    if (idx >= LL * 3 * 96 * 32) return;
    int j = idx & 7;
    int q = (idx >> 3) & 3;
    int rest = idx >> 5;
    int n = rest % 96;
    int rest2 = rest / 96;
    int ks = rest2 % 3;
    int l = rest2 / 3;
    int k = ks * 32 + q * 8 + j;
    Wp[idx] = f2bf(W[(size_t)l * 96 * 96 + (size_t)k * 96 + n]);
}

// Wg[k][n]: k<96 from wih (agg side), k>=96 from whh (h side).
// n in [0,192): r/z sums; [192,288): i_n (wih only); [288,384): h_n (whh only)
__global__ void packWgp_k(const float* __restrict__ wih, const float* __restrict__ whh,
                          unsigned short* __restrict__ Wgp)
{
    int idx = blockIdx.x * 256 + threadIdx.x;
    if (idx >= 6 * 384 * 32) return;
    int j = idx & 7;
    int q = (idx >> 3) & 3;
    int rest = idx >> 5;
    int n = rest % 384;
    int ks = rest / 384;
    int k = ks * 32 + q * 8 + j;
    float v;
    if (n < 192) {
        v = (k < 96) ? wih[(size_t)n * 96 + k] : whh[(size_t)n * 96 + (k - 96)];
    } else if (n < 288) {
        int jj = n - 192;
        v = (k < 96) ? wih[(size_t)(192 + jj) * 96 + k] : 0.f;
    } else {
        int jj = n - 288;
        v = (k < 96) ? 0.f : whh[(size_t)(192 + jj) * 96 + (k - 96)];
    }
    Wgp[idx] = f2bf(v);
}

__global__ void pad_k(const float* __restrict__ x, float* __restrict__ h)
{
    int idx = blockIdx.x * 256 + threadIdx.x;
    if (idx >= NN_ * HH) return;
    int n = idx / HH, j = idx % HH;
    h[idx] = (j < 32) ? x[n * 32 + j] : 0.f;
}

// --------------------------- CSR build (once per component) -----------------
__global__ void deg_k(const int* __restrict__ ei, int* __restrict__ deg)
{
    int e = blockIdx.x * 256 + threadIdx.x;
    if (e >= EE_) return;
    atomicAdd(&deg[ei[EE_ + e]], 1);
}

__global__ __launch_bounds__(SCAN_B) void scan1_k(
    const int* __restrict__ deg, int* __restrict__ rp, int* __restrict__ bsum)
{
    __shared__ int sh[SCAN_B];
    int i = blockIdx.x * SCAN_B + threadIdx.x;
    int v = (i < NN_) ? deg[i] : 0;
    sh[threadIdx.x] = v;
    __syncthreads();
    for (int off = 1; off < SCAN_B; off <<= 1) {
        int t = (threadIdx.x >= off) ? sh[threadIdx.x - off] : 0;
        __syncthreads();
        sh[threadIdx.x] += t;
        __syncthreads();
    }
    if (i < NN_) rp[i] = sh[threadIdx.x] - v;     // exclusive within block
    if (threadIdx.x == SCAN_B - 1) bsum[blockIdx.x] = sh[threadIdx.x];
}

__global__ __launch_bounds__(256) void scan2_k(int* __restrict__ bsum)
{
    __shared__ int sh[256];
    int v = (threadIdx.x < NB_SCAN) ? bsum[threadIdx.x] : 0;
    sh[threadIdx.x] = v;
    __syncthreads();
    for (int off = 1; off < 256; off <<= 1) {
        int t = (threadIdx.x >= off) ? sh[threadIdx.x - off] : 0;
        __syncthreads();
        sh[threadIdx.x] += t;
        __syncthreads();
    }
    if (threadIdx.x < NB_SCAN) bsum[threadIdx.x] = sh[threadIdx.x] - v;  // exclusive
}

__global__ void scan3_k(int* __restrict__ rp, const int* __restrict__ bsum,
                        int* __restrict__ cur)
{
    int i = blockIdx.x * 256 + threadIdx.x;
    if (i < NN_) {
        int r = rp[i] + bsum[i / SCAN_B];
        rp[i] = r;
        cur[i] = r;
    }
    if (i == 0) rp[NN_] = EE_;
}

__global__ void fill_k(const int* __restrict__ ei, int* __restrict__ cur,
                       int* __restrict__ srcs)
{
    int e = blockIdx.x * 256 + threadIdx.x;
    if (e >= EE_) return;
    int s = ei[e];
    int d = ei[EE_ + e];
    int pos = atomicAdd(&cur[d], 1);
    srcs[pos] = s;
}

// batch row pointers: batch[] is sorted, detect segment boundaries.
// rpb[q] = first node index with batch >= q; rpb[BB] = NN_.
__global__ void brp_k(const int* __restrict__ bat, int* __restrict__ rpb)
{
    int i = blockIdx.x * 256 + threadIdx.x;
    if (i >= NN_) return;
    int b = bat[i];
    if (i == 0) {
        for (int q = 0; q <= b; q++) rpb[q] = 0;
    } else {
        int p = bat[i - 1];
        for (int q = p + 1; q <= b; q++) rpb[q] = i;
    }
    if (i == NN_ - 1) {
        for (int q = b + 1; q <= BB; q++) rpb[q] = NN_;
    }
}

// ---------------------------------------------------------------------------
// m_bf = bf16( bf16(h) @ W[l] )  (bf16 MFMA, fp32 acc). 64 rows/block.
// ---------------------------------------------------------------------------
__global__ __launch_bounds__(256) void gemm1_mfma(
    const float* __restrict__ h,
    const unsigned short* __restrict__ Wp,   // this layer's pack: [3][96][4][8]
    unsigned short* __restrict__ m_bf)
{
    int wave = threadIdx.x >> 6;
    int lane = threadIdx.x & 63;
    int quad = lane >> 4;
    int lc   = lane & 15;
    int rowA = blockIdx.x * 64 + wave * 16 + lc;

    f4v acc[6] = {};
    #pragma unroll
    for (int ks = 0; ks < 3; ks++) {
        s8v a = load_bf8(h + (size_t)rowA * 96 + ks * 32 + quad * 8);
        #pragma unroll
        for (int t = 0; t < 6; t++) {
            s8v b = *(const s8v*)(Wp + ((size_t)(ks * 96 + t * 16 + lc) * 4 + quad) * 8);
            acc[t] = __builtin_amdgcn_mfma_f32_16x16x32_bf16(a, b, acc[t], 0, 0, 0);
        }
    }
    int rowD = blockIdx.x * 64 + wave * 16 + quad * 4;
    #pragma unroll
    for (int t = 0; t < 6; t++) {
        #pragma unroll
        for (int r = 0; r < 4; r++) {
            m_bf[(size_t)(rowD + r) * 96 + t * 16 + lc] = f2bf(acc[t][r]);
        }
    }
}

// ---------------------------------------------------------------------------
// CSR aggregation: agg_bf[n] = bf16( sum_{e in CSR[n]} m_bf[srcs[e]] ).
// ---------------------------------------------------------------------------
__global__ void agg_csr_k(const unsigned short* __restrict__ m_bf,
                          const int* __restrict__ rp, const int* __restrict__ srcs,
                          unsigned short* __restrict__ agg_bf)
{
    int idx = blockIdx.x * 256 + threadIdx.x;
    if (idx >= NN_ * 12) return;
    int node = idx / 12;
    int g = (idx % 12) * 8;
    int e0 = rp[node], e1 = rp[node + 1];
    float s0 = 0.f, s1 = 0.f, s2 = 0.f, s3 = 0.f;
    float s4 = 0.f, s5 = 0.f, s6 = 0.f, s7 = 0.f;
    for (int e = e0; e < e1; e++) {
        int sr = srcs[e];
        uint4 u = *(const uint4*)(m_bf + (size_t)sr * 96 + g);
        s0 += bf2f((unsigned short)(u.x & 0xFFFF));
        s1 += bf2f((unsigned short)(u.x >> 16));
        s2 += bf2f((unsigned short)(u.y & 0xFFFF));
        s3 += bf2f((unsigned short)(u.y >> 16));
        s4 += bf2f((unsigned short)(u.z & 0xFFFF));
        s5 += bf2f((unsigned short)(u.z >> 16));
        s6 += bf2f((unsigned short)(u.w & 0xFFFF));
        s7 += bf2f((unsigned short)(u.w >> 16));
    }
    uint4 o;
    o.x = (unsigned)f2bf(s0) | ((unsigned)f2bf(s1) << 16);
    o.y = (unsigned)f2bf(s2) | ((unsigned)f2bf(s3) << 16);
    o.z = (unsigned)f2bf(s4) | ((unsigned)f2bf(s5) << 16);
    o.w = (unsigned)f2bf(s6) | ((unsigned)f2bf(s7) << 16);
    *(uint4*)(agg_bf + (size_t)node * 96 + g) = o;
}

// ---------------------------------------------------------------------------
// Fused GRU: G = [agg_bf | bf16(h)] @ Wg (192x384 bf16 MFMA); GRUCell applied
// lane-locally in the epilogue. Updates h in place.
// ---------------------------------------------------------------------------
__global__ __launch_bounds__(256) void gru_mfma(
    const unsigned short* __restrict__ agg_bf,
    const unsigned short* __restrict__ Wgp,
    const float* __restrict__ bih, const float* __restrict__ bhh,
    float* __restrict__ h)
{
    int wave = threadIdx.x >> 6;
    int lane = threadIdx.x & 63;
    int quad = lane >> 4;
    int lc   = lane & 15;
    int rowA = blockIdx.x * 64 + wave * 16 + lc;

    f4v acc[24] = {};
    #pragma unroll
    for (int ks = 0; ks < 3; ks++) {
        s8v a = *(const s8v*)(agg_bf + (size_t)rowA * 96 + ks * 32 + quad * 8);
        #pragma unroll
        for (int t = 0; t < 24; t++) {
            s8v b = *(const s8v*)(Wgp + ((size_t)(ks * 384 + t * 16 + lc) * 4 + quad) * 8);
            acc[t] = __builtin_amdgcn_mfma_f32_16x16x32_bf16(a, b, acc[t], 0, 0, 0);
        }
    }
    #pragma unroll
    for (int ks = 0; ks < 3; ks++) {
        s8v a = load_bf8(h + (size_t)rowA * 96 + ks * 32 + quad * 8);
        #pragma unroll
        for (int t = 0; t < 24; t++) {
            s8v b = *(const s8v*)(Wgp + ((size_t)((ks + 3) * 384 + t * 16 + lc) * 4 + quad) * 8);
            acc[t] = __builtin_amdgcn_mfma_f32_16x16x32_bf16(a, b, acc[t], 0, 0, 0);
        }
    }
    int rowD = blockIdx.x * 64 + wave * 16 + quad * 4;
    #pragma unroll
    for (int t = 0; t < 6; t++) {
        int j = t * 16 + lc;
        float bi_r = bih[j],       bh_r = bhh[j];
        float bi_z = bih[96 + j],  bh_z = bhh[96 + j];
        float bi_n = bih[192 + j], bh_n = bhh[192 + j];
        #pragma unroll
        for (int r = 0; r < 4; r++) {
            float rg = sigmoidf_(acc[t][r]      + bi_r + bh_r);
            float zg = sigmoidf_(acc[t + 6][r]  + bi_z + bh_z);
            float nn = tanhf_(acc[t + 12][r] + bi_n + rg * (acc[t + 18][r] + bh_n));
            size_t hi = (size_t)(rowD + r) * 96 + j;
            float hv = h[hi];
            h[hi] = (1.f - zg) * nn + zg * hv;
        }
    }
}

// ---------------------------------------------------------------------------
// Mean pool via sorted-batch segments: one block per graph, no atomics.
// ---------------------------------------------------------------------------
__global__ __launch_bounds__(128) void pool_csr_k(
    const float* __restrict__ h, const int* __restrict__ rpb, float* __restrict__ g)
{
    int b = blockIdx.x;
    int j = threadIdx.x;
    if (j >= 96) return;
    int n0 = rpb[b], n1 = rpb[b + 1];
    float s = 0.f;
    for (int n = n0; n < n1; n++) s += fmaxf(h[(size_t)n * 96 + j], 0.f);
    float c = (float)(n1 - n0);
    g[(size_t)b * 96 + j] = s / fmaxf(c, 1.f);
}

__global__ void feat_k(const float* __restrict__ g1, const float* __restrict__ g2,
                       const float* __restrict__ g3, float* __restrict__ feat)
{
    int idx = blockIdx.x * 256 + threadIdx.x;
    if (idx >= BB * HH) return;
    int b = idx / HH, j = idx % HH;
    float a = g1[idx], bb = g2[idx], c = g3[idx];
    float* f = feat + (size_t)b * 384;
    f[j]       = a;
    f[96 + j]  = bb;
    f[192 + j] = c;
    f[288 + j] = a * bb * c;
}

// ---------------------------------------------------------------------------
// MLP GEMM: C[M,N] = relu(bf16(A[M,K]) @ Bp + bias). M%64==0, N%128==0 in grid
// terms (N%16==0 with grid.x = N/128), K%32==0. Block 256 = 4 waves x 16 rows.
// ---------------------------------------------------------------------------
__global__ __launch_bounds__(256) void gemm_mlp_mfma(
    const float* __restrict__ A, const unsigned short* __restrict__ Bp,
    const float* __restrict__ bias, float* __restrict__ C,
    int K, int N, int doRelu)
{
    int wave = threadIdx.x >> 6;
    int lane = threadIdx.x & 63;
    int quad = lane >> 4;
    int lc   = lane & 15;
    int rowA = blockIdx.y * 64 + wave * 16 + lc;
    int colb = blockIdx.x * 128;

    f4v acc[8] = {};
    for (int ks = 0; ks < K / 32; ks++) {
        s8v a = load_bf8(A + (size_t)rowA * K + ks * 32 + quad * 8);
        #pragma unroll
        for (int t = 0; t < 8; t++) {
            int n = colb + t * 16 + lc;
            s8v b = *(const s8v*)(Bp + ((size_t)(ks * N + n) * 4 + quad) * 8);
            acc[t] = __builtin_amdgcn_mfma_f32_16x16x32_bf16(a, b, acc[t], 0, 0, 0);
        }
    }
    int rowD = blockIdx.y * 64 + wave * 16 + quad * 4;
    #pragma unroll
    for (int t = 0; t < 8; t++) {
        int n = colb + t * 16 + lc;
        float bv = bias[n];
        #pragma unroll
        for (int r = 0; r < 4; r++) {
            float v = acc[t][r] + bv;
            if (doRelu) v = fmaxf(v, 0.f);
            C[(size_t)(rowD + r) * N + n] = v;
        }
    }
}

// fc3: one wave per graph, shuffle reduction. grid 1024 x 256.
__global__ __launch_bounds__(256) void fc3_k(const float* __restrict__ t2,
                                             const float* __restrict__ w,
                                             const float* __restrict__ bias,
                                             float* __restrict__ out)
{
    int wave = threadIdx.x >> 6;
    int lane = threadIdx.x & 63;
    int b = blockIdx.x * 4 + wave;
    const float* row = t2 + (size_t)b * 384;
    float a0 = 0.f, a1 = 0.f, a2 = 0.f;
    #pragma unroll
    for (int kk = 0; kk < 6; kk++) {
        int k = kk * 64 + lane;
        float x = row[k];
        a0 += x * w[k * 3 + 0];
        a1 += x * w[k * 3 + 1];
        a2 += x * w[k * 3 + 2];
    }
    #pragma unroll
    for (int off = 32; off > 0; off >>= 1) {
        a0 += __shfl_down(a0, off);
        a1 += __shfl_down(a1, off);
        a2 += __shfl_down(a2, off);
    }
    if (lane == 0) {
        out[b * 3 + 0] = a0 + bias[0];
        out[b * 3 + 1] = a1 + bias[1];
        out[b * 3 + 2] = a2 + bias[2];
    }
}

extern "C" void kernel_launch(void* const* d_in, const int* in_sizes, int n_in,
                              void* d_out, int out_size, void* d_ws, size_t ws_size,
                              hipStream_t stream)
{
    // Workspace (floats). Total ~41.3M f = 165 MB (237 MB proven safe).
    float* ws    = (float*)d_ws;
    float* h     = ws;                               // 19,200,000
    float* mbfF  = h + (size_t)NN_ * HH;             //  9,600,000 (19.2M bf16)
    float* abfF  = mbfF + (size_t)NN_ * HH / 2;      //  9,600,000 (19.2M bf16)
    float* wpF   = abfF + (size_t)NN_ * HH / 2;      //     27,648
    float* wgpF  = wpF + 27648;                      //     36,864
    float* fc1pF = wgpF + 36864;                     //    294,912 (589,824 bf16)
    float* fc2pF = fc1pF + 294912;                   //    294,912
    float* g3    = fc2pF + 294912;                   //  1,179,648
    int*   rp    = (int*)(g3 + 3 * (size_t)BB * HH); //    200,064 ints
    int*   srcs  = rp + 200064;                      //    400,000 ints
    int*   deg   = srcs + 400000;                    //    200,000 ints
    int*   cur   = deg + 200000;                     //    200,000 ints
    int*   bsum  = cur + 200000;                     //        256 ints
    int*   rpb   = bsum + 256;                       //      4,097 ints

    unsigned short* m_bf   = (unsigned short*)mbfF;
    unsigned short* agg_bf = (unsigned short*)abfF;
    unsigned short* Wp     = (unsigned short*)wpF;
    unsigned short* Wgp    = (unsigned short*)wgpF;
    unsigned short* fc1p   = (unsigned short*)fc1pF;
    unsigned short* fc2p   = (unsigned short*)fc2pF;

    // MLP temps alias h (dead after pooling)
    float* feat = h;
    float* t1   = h + 2 * 1024 * 1024;
    float* t2   = h + 9 * 1024 * 1024;

    for (int c = 0; c < 3; c++) {
        const float* x   = (const float*)d_in[c * 8 + 0];
        const int*   ei  = (const int*)  d_in[c * 8 + 1];
        const int*   bat = (const int*)  d_in[c * 8 + 2];
        const float* W   = (const float*)d_in[c * 8 + 3];
        const float* wih = (const float*)d_in[c * 8 + 4];
        const float* whh = (const float*)d_in[c * 8 + 5];
        const float* bih = (const float*)d_in[c * 8 + 6];
        const float* bhh = (const float*)d_in[c * 8 + 7];

        // CSR build (once per component, reused for all 6 layers)
        hipMemsetAsync(deg, 0, NN_ * sizeof(int), stream);
        deg_k<<<cdiv(EE_, 256), 256, 0, stream>>>(ei, deg);
        scan1_k<<<NB_SCAN, SCAN_B, 0, stream>>>(deg, rp, bsum);
        scan2_k<<<1, 256, 0, stream>>>(bsum);
        scan3_k<<<cdiv(NN_, 256), 256, 0, stream>>>(rp, bsum, cur);
        fill_k<<<cdiv(EE_, 256), 256, 0, stream>>>(ei, cur, srcs);
        brp_k<<<cdiv(NN_, 256), 256, 0, stream>>>(bat, rpb);

        packWp_k<<<cdiv(LL * 3 * 96 * 32, 256), 256, 0, stream>>>(W, Wp);
        packWgp_k<<<cdiv(6 * 384 * 32, 256), 256, 0, stream>>>(wih, whh, Wgp);
        pad_k<<<cdiv(NN_ * HH, 256), 256, 0, stream>>>(x, h);

        for (int l = 0; l < LL; l++) {
            gemm1_mfma<<<NN_ / 64, 256, 0, stream>>>(h, Wp + (size_t)l * 3 * 96 * 32, m_bf);
            agg_csr_k<<<cdiv(NN_ * 12, 256), 256, 0, stream>>>(m_bf, rp, srcs, agg_bf);
            gru_mfma<<<NN_ / 64, 256, 0, stream>>>(agg_bf, Wgp, bih, bhh, h);
        }

        pool_csr_k<<<BB, 128, 0, stream>>>(h, rpb, g3 + (size_t)c * BB * HH);
    }

    const float* fc1_w = (const float*)d_in[24];
    const float* fc1_b = (const float*)d_in[25];
    const float* fc2_w = (const float*)d_in[26];
    const float* fc2_b = (const float*)d_in[27];
    const float* fc3_w = (const float*)d_in[28];
    const float* fc3_b = (const float*)d_in[29];

    packB_k<<<cdiv(384 * 1536, 256), 256, 0, stream>>>(fc1_w, fc1p, 384, 1536);
    packB_k<<<cdiv(1536 * 384, 256), 256, 0, stream>>>(fc2_w, fc2p, 1536, 384);

    feat_k<<<cdiv(BB * HH, 256), 256, 0, stream>>>(
        g3, g3 + (size_t)BB * HH, g3 + 2 * (size_t)BB * HH, feat);
    gemm_mlp_mfma<<<dim3(1536 / 128, BB / 64), 256, 0, stream>>>(
        feat, fc1p, fc1_b, t1, 384, 1536, 1);
    gemm_mlp_mfma<<<dim3(384 / 128, BB / 64), 256, 0, stream>>>(
        t1, fc2p, fc2_b, t2, 1536, 384, 1);
    fc3_k<<<BB / 4, 256, 0, stream>>>(t2, fc3_w, fc3_b, (float*)d_out);
}

// Round 7
// 3835.970 us; speedup vs baseline: 5.5939x; 1.3189x over previous
//
#include <hip/hip_runtime.h>
#include <math.h>

#define NN_ 200000
#define EE_ 400000
#define HH  96
#define LL  6
#define BB  4096
#define SCAN_B 1024
#define NB_SCAN 196   // cdiv(200000, 1024)

typedef short s8v __attribute__((ext_vector_type(8)));
typedef float f4v __attribute__((ext_vector_type(4)));

static inline int cdiv(int a, int b) { return (a + b - 1) / b; }

__device__ __forceinline__ float sigmoidf_(float x) { return 1.0f / (1.0f + __expf(-x)); }
__device__ __forceinline__ float tanhf_(float x) { return 1.0f - 2.0f / (__expf(2.0f * x) + 1.0f); }
__device__ __forceinline__ unsigned short f2bf(float x) {
    unsigned u = __float_as_uint(x);
    unsigned r = u + 0x7FFF + ((u >> 16) & 1);   // RNE
    return (unsigned short)(r >> 16);
}
__device__ __forceinline__ float bf2f(unsigned short u) {
    return __uint_as_float(((unsigned)u) << 16);
}
// load 8 consecutive fp32 and convert to a bf16x8 MFMA fragment (in-register)
__device__ __forceinline__ s8v load_bf8(const float* __restrict__ p) {
    float4 v0 = *(const float4*)p;
    float4 v1 = *(const float4*)(p + 4);
    s8v r;
    r[0] = (short)f2bf(v0.x); r[1] = (short)f2bf(v0.y);
    r[2] = (short)f2bf(v0.z); r[3] = (short)f2bf(v0.w);
    r[4] = (short)f2bf(v1.x); r[5] = (short)f2bf(v1.y);
    r[6] = (short)f2bf(v1.z); r[7] = (short)f2bf(v1.w);
    return r;
}

// ---------------------------------------------------------------------------
// Weight packing into MFMA B-fragment order (bf16).
// Bp[((k>>5)*N + n)*32 + ((k>>3)&3)*8 + (k&7)] = bf16(B[k*N + n])
// ---------------------------------------------------------------------------
__global__ void packB_k(const float* __restrict__ B, unsigned short* __restrict__ Bp,
                        int K, int N)
{
    int idx = blockIdx.x * 256 + threadIdx.x;
    if (idx >= K * N) return;
    int k = idx / N, n = idx % N;
    Bp[(((size_t)(k >> 5) * N + n) * 4 + ((k >> 3) & 3)) * 8 + (k & 7)] = f2bf(B[idx]);
}

__global__ void packWp_k(const float* __restrict__ W, unsigned short* __restrict__ Wp)
{
    int idx = blockIdx.x * 256 + threadIdx.x;
    if (idx >= LL * 3 * 96 * 32) return;
    int j = idx & 7;
    int q = (idx >> 3) & 3;
    int rest = idx >> 5;
    int n = rest % 96;
    int rest2 = rest / 96;
    int ks = rest2 % 3;
    int l = rest2 / 3;
    int k = ks * 32 + q * 8 + j;
    Wp[idx] = f2bf(W[(size_t)l * 96 * 96 + (size_t)k * 96 + n]);
}

// Wg[k][n]: k<96 from wih (agg side), k>=96 from whh (h side).
// n in [0,192): r/z sums; [192,288): i_n (wih only); [288,384): h_n (whh only)
__global__ void packWgp_k(const float* __restrict__ wih, const float* __restrict__ whh,
                          unsigned short* __restrict__ Wgp)
{
    int idx = blockIdx.x * 256 + threadIdx.x;
    if (idx >= 6 * 384 * 32) return;
    int j = idx & 7;
    int q = (idx >> 3) & 3;
    int rest = idx >> 5;
    int n = rest % 384;
    int ks = rest / 384;
    int k = ks * 32 + q * 8 + j;
    float v;
    if (n < 192) {
        v = (k < 96) ? wih[(size_t)n * 96 + k] : whh[(size_t)n * 96 + (k - 96)];
    } else if (n < 288) {
        int jj = n - 192;
        v = (k < 96) ? wih[(size_t)(192 + jj) * 96 + k] : 0.f;
    } else {
        int jj = n - 288;
        v = (k < 96) ? 0.f : whh[(size_t)(192 + jj) * 96 + (k - 96)];
    }
    Wgp[idx] = f2bf(v);
}

__global__ void pad_k(const float* __restrict__ x, float* __restrict__ h)
{
    int idx = blockIdx.x * 256 + threadIdx.x;
    if (idx >= NN_ * HH) return;
    int n = idx / HH, j = idx % HH;
    h[idx] = (j < 32) ? x[n * 32 + j] : 0.f;
}

// --------------------------- CSR build (once per component) -----------------
__global__ void deg_k(const int* __restrict__ ei, int* __restrict__ deg)
{
    int e = blockIdx.x * 256 + threadIdx.x;
    if (e >= EE_) return;
    atomicAdd(&deg[ei[EE_ + e]], 1);
}

__global__ __launch_bounds__(SCAN_B) void scan1_k(
    const int* __restrict__ deg, int* __restrict__ rp, int* __restrict__ bsum)
{
    __shared__ int sh[SCAN_B];
    int i = blockIdx.x * SCAN_B + threadIdx.x;
    int v = (i < NN_) ? deg[i] : 0;
    sh[threadIdx.x] = v;
    __syncthreads();
    for (int off = 1; off < SCAN_B; off <<= 1) {
        int t = (threadIdx.x >= off) ? sh[threadIdx.x - off] : 0;
        __syncthreads();
        sh[threadIdx.x] += t;
        __syncthreads();
    }
    if (i < NN_) rp[i] = sh[threadIdx.x] - v;     // exclusive within block
    if (threadIdx.x == SCAN_B - 1) bsum[blockIdx.x] = sh[threadIdx.x];
}

__global__ __launch_bounds__(256) void scan2_k(int* __restrict__ bsum)
{
    __shared__ int sh[256];
    int v = (threadIdx.x < NB_SCAN) ? bsum[threadIdx.x] : 0;
    sh[threadIdx.x] = v;
    __syncthreads();
    for (int off = 1; off < 256; off <<= 1) {
        int t = (threadIdx.x >= off) ? sh[threadIdx.x - off] : 0;
        __syncthreads();
        sh[threadIdx.x] += t;
        __syncthreads();
    }
    if (threadIdx.x < NB_SCAN) bsum[threadIdx.x] = sh[threadIdx.x] - v;  // exclusive
}

__global__ void scan3_k(int* __restrict__ rp, const int* __restrict__ bsum,
                        int* __restrict__ cur)
{
    int i = blockIdx.x * 256 + threadIdx.x;
    if (i < NN_) {
        int r = rp[i] + bsum[i / SCAN_B];
        rp[i] = r;
        cur[i] = r;
    }
    if (i == 0) rp[NN_] = EE_;
}

__global__ void fill_k(const int* __restrict__ ei, int* __restrict__ cur,
                       int* __restrict__ srcs)
{
    int e = blockIdx.x * 256 + threadIdx.x;
    if (e >= EE_) return;
    int s = ei[e];
    int d = ei[EE_ + e];
    int pos = atomicAdd(&cur[d], 1);
    srcs[pos] = s;
}

// batch row pointers: batch[] is sorted, detect segment boundaries.
__global__ void brp_k(const int* __restrict__ bat, int* __restrict__ rpb)
{
    int i = blockIdx.x * 256 + threadIdx.x;
    if (i >= NN_) return;
    int b = bat[i];
    if (i == 0) {
        for (int q = 0; q <= b; q++) rpb[q] = 0;
    } else {
        int p = bat[i - 1];
        for (int q = p + 1; q <= b; q++) rpb[q] = i;
    }
    if (i == NN_ - 1) {
        for (int q = b + 1; q <= BB; q++) rpb[q] = NN_;
    }
}

// ---------------------------------------------------------------------------
// m_bf = bf16( bf16(h) @ W[l] ). B (18.4 KB) staged in LDS once, then
// conflict-free ds_read_b128 fragments. 64 rows/block, 4 waves x 16 rows.
// ---------------------------------------------------------------------------
__global__ __launch_bounds__(256) void gemm1_mfma(
    const float* __restrict__ h,
    const unsigned short* __restrict__ Wp,   // this layer's pack: [3][96][4][8]
    unsigned short* __restrict__ m_bf)
{
    __shared__ unsigned short Ws[9216];      // 18,432 B
    int tid  = threadIdx.x;
    int wave = tid >> 6;
    int lane = tid & 63;
    int quad = lane >> 4;
    int lc   = lane & 15;
    int rowA = blockIdx.x * 64 + wave * 16 + lc;

    {
        const uint4* src = (const uint4*)Wp;
        uint4* dst = (uint4*)Ws;
        #pragma unroll
        for (int i = 0; i < 5; i++) {
            int idx = i * 256 + tid;
            if (idx < 1152) dst[idx] = src[idx];
        }
    }
    __syncthreads();

    f4v acc[6] = {};
    #pragma unroll
    for (int ks = 0; ks < 3; ks++) {
        s8v a = load_bf8(h + (size_t)rowA * 96 + ks * 32 + quad * 8);
        #pragma unroll
        for (int t = 0; t < 6; t++) {
            s8v b = *(const s8v*)(Ws + ((size_t)(ks * 96 + t * 16 + lc) * 4 + quad) * 8);
            acc[t] = __builtin_amdgcn_mfma_f32_16x16x32_bf16(a, b, acc[t], 0, 0, 0);
        }
    }
    int rowD = blockIdx.x * 64 + wave * 16 + quad * 4;
    #pragma unroll
    for (int t = 0; t < 6; t++) {
        #pragma unroll
        for (int r = 0; r < 4; r++) {
            m_bf[(size_t)(rowD + r) * 96 + t * 16 + lc] = f2bf(acc[t][r]);
        }
    }
}

// ---------------------------------------------------------------------------
// CSR aggregation: agg_bf[n] = bf16( sum_{e in CSR[n]} m_bf[srcs[e]] ).
// ---------------------------------------------------------------------------
__global__ void agg_csr_k(const unsigned short* __restrict__ m_bf,
                          const int* __restrict__ rp, const int* __restrict__ srcs,
                          unsigned short* __restrict__ agg_bf)
{
    int idx = blockIdx.x * 256 + threadIdx.x;
    if (idx >= NN_ * 12) return;
    int node = idx / 12;
    int g = (idx % 12) * 8;
    int e0 = rp[node], e1 = rp[node + 1];
    float s0 = 0.f, s1 = 0.f, s2 = 0.f, s3 = 0.f;
    float s4 = 0.f, s5 = 0.f, s6 = 0.f, s7 = 0.f;
    for (int e = e0; e < e1; e++) {
        int sr = srcs[e];
        uint4 u = *(const uint4*)(m_bf + (size_t)sr * 96 + g);
        s0 += bf2f((unsigned short)(u.x & 0xFFFF));
        s1 += bf2f((unsigned short)(u.x >> 16));
        s2 += bf2f((unsigned short)(u.y & 0xFFFF));
        s3 += bf2f((unsigned short)(u.y >> 16));
        s4 += bf2f((unsigned short)(u.z & 0xFFFF));
        s5 += bf2f((unsigned short)(u.z >> 16));
        s6 += bf2f((unsigned short)(u.w & 0xFFFF));
        s7 += bf2f((unsigned short)(u.w >> 16));
    }
    uint4 o;
    o.x = (unsigned)f2bf(s0) | ((unsigned)f2bf(s1) << 16);
    o.y = (unsigned)f2bf(s2) | ((unsigned)f2bf(s3) << 16);
    o.z = (unsigned)f2bf(s4) | ((unsigned)f2bf(s5) << 16);
    o.w = (unsigned)f2bf(s6) | ((unsigned)f2bf(s7) << 16);
    *(uint4*)(agg_bf + (size_t)node * 96 + g) = o;
}

// ---------------------------------------------------------------------------
// Fused GRU: G = [agg_bf | bf16(h)] @ Wg (192x384 bf16 MFMA). Wgp staged in
// LDS, double-buffered per 32-k slice (2 x 24.5 KB); fragments then come from
// conflict-free ds_read_b128 instead of 144 L2 round-trips per wave.
// GRUCell epilogue lane-local (cols j,96+j,192+j,288+j sit in acc tiles
// t,t+6,t+12,t+18). Same accumulation order as Round 6 -> bit-identical.
// ---------------------------------------------------------------------------
__global__ __launch_bounds__(256) void gru_mfma(
    const unsigned short* __restrict__ agg_bf,
    const unsigned short* __restrict__ Wgp,
    const float* __restrict__ bih, const float* __restrict__ bhh,
    float* __restrict__ h)
{
    __shared__ unsigned short Bs[2][12288];  // 2 x 24,576 B
    int tid  = threadIdx.x;
    int wave = tid >> 6;
    int lane = tid & 63;
    int quad = lane >> 4;
    int lc   = lane & 15;
    int rowA = blockIdx.x * 64 + wave * 16 + lc;

    // stage slice 0
    {
        const uint4* src = (const uint4*)Wgp;
        uint4* dst = (uint4*)&Bs[0][0];
        #pragma unroll
        for (int i = 0; i < 6; i++) dst[i * 256 + tid] = src[i * 256 + tid];
    }
    __syncthreads();

    f4v acc[24] = {};
    #pragma unroll
    for (int ks = 0; ks < 6; ks++) {
        if (ks < 5) {   // prefetch next slice into the other buffer
            const uint4* src = (const uint4*)(Wgp + (size_t)(ks + 1) * 12288);
            uint4* dst = (uint4*)&Bs[(ks + 1) & 1][0];
            #pragma unroll
            for (int i = 0; i < 6; i++) dst[i * 256 + tid] = src[i * 256 + tid];
        }
        s8v a;
        if (ks < 3) a = *(const s8v*)(agg_bf + (size_t)rowA * 96 + ks * 32 + quad * 8);
        else        a = load_bf8(h + (size_t)rowA * 96 + (ks - 3) * 32 + quad * 8);
        const unsigned short* B = &Bs[ks & 1][0];
        #pragma unroll
        for (int t = 0; t < 24; t++) {
            s8v b = *(const s8v*)(B + ((t * 16 + lc) * 4 + quad) * 8);
            acc[t] = __builtin_amdgcn_mfma_f32_16x16x32_bf16(a, b, acc[t], 0, 0, 0);
        }
        __syncthreads();
    }
    int rowD = blockIdx.x * 64 + wave * 16 + quad * 4;
    #pragma unroll
    for (int t = 0; t < 6; t++) {
        int j = t * 16 + lc;
        float bi_r = bih[j],       bh_r = bhh[j];
        float bi_z = bih[96 + j],  bh_z = bhh[96 + j];
        float bi_n = bih[192 + j], bh_n = bhh[192 + j];
        #pragma unroll
        for (int r = 0; r < 4; r++) {
            float rg = sigmoidf_(acc[t][r]      + bi_r + bh_r);
            float zg = sigmoidf_(acc[t + 6][r]  + bi_z + bh_z);
            float nn = tanhf_(acc[t + 12][r] + bi_n + rg * (acc[t + 18][r] + bh_n));
            size_t hi = (size_t)(rowD + r) * 96 + j;
            float hv = h[hi];
            h[hi] = (1.f - zg) * nn + zg * hv;
        }
    }
}

// ---------------------------------------------------------------------------
// Mean pool via sorted-batch segments: one block per graph, no atomics.
// ---------------------------------------------------------------------------
__global__ __launch_bounds__(128) void pool_csr_k(
    const float* __restrict__ h, const int* __restrict__ rpb, float* __restrict__ g)
{
    int b = blockIdx.x;
    int j = threadIdx.x;
    if (j >= 96) return;
    int n0 = rpb[b], n1 = rpb[b + 1];
    float s = 0.f;
    for (int n = n0; n < n1; n++) s += fmaxf(h[(size_t)n * 96 + j], 0.f);
    float c = (float)(n1 - n0);
    g[(size_t)b * 96 + j] = s / fmaxf(c, 1.f);
}

__global__ void feat_k(const float* __restrict__ g1, const float* __restrict__ g2,
                       const float* __restrict__ g3, float* __restrict__ feat)
{
    int idx = blockIdx.x * 256 + threadIdx.x;
    if (idx >= BB * HH) return;
    int b = idx / HH, j = idx % HH;
    float a = g1[idx], bb = g2[idx], c = g3[idx];
    float* f = feat + (size_t)b * 384;
    f[j]       = a;
    f[96 + j]  = bb;
    f[192 + j] = c;
    f[288 + j] = a * bb * c;
}

// ---------------------------------------------------------------------------
// MLP GEMM: C[M,N] = relu(bf16(A[M,K]) @ Bp + bias).
// ---------------------------------------------------------------------------
__global__ __launch_bounds__(256) void gemm_mlp_mfma(
    const float* __restrict__ A, const unsigned short* __restrict__ Bp,
    const float* __restrict__ bias, float* __restrict__ C,
    int K, int N, int doRelu)
{
    int wave = threadIdx.x >> 6;
    int lane = threadIdx.x & 63;
    int quad = lane >> 4;
    int lc   = lane & 15;
    int rowA = blockIdx.y * 64 + wave * 16 + lc;
    int colb = blockIdx.x * 128;

    f4v acc[8] = {};
    for (int ks = 0; ks < K / 32; ks++) {
        s8v a = load_bf8(A + (size_t)rowA * K + ks * 32 + quad * 8);
        #pragma unroll
        for (int t = 0; t < 8; t++) {
            int n = colb + t * 16 + lc;
            s8v b = *(const s8v*)(Bp + ((size_t)(ks * N + n) * 4 + quad) * 8);
            acc[t] = __builtin_amdgcn_mfma_f32_16x16x32_bf16(a, b, acc[t], 0, 0, 0);
        }
    }
    int rowD = blockIdx.y * 64 + wave * 16 + quad * 4;
    #pragma unroll
    for (int t = 0; t < 8; t++) {
        int n = colb + t * 16 + lc;
        float bv = bias[n];
        #pragma unroll
        for (int r = 0; r < 4; r++) {
            float v = acc[t][r] + bv;
            if (doRelu) v = fmaxf(v, 0.f);
            C[(size_t)(rowD + r) * N + n] = v;
        }
    }
}

// fc3: one wave per graph, shuffle reduction.
__global__ __launch_bounds__(256) void fc3_k(const float* __restrict__ t2,
                                             const float* __restrict__ w,
                                             const float* __restrict__ bias,
                                             float* __restrict__ out)
{
    int wave = threadIdx.x >> 6;
    int lane = threadIdx.x & 63;
    int b = blockIdx.x * 4 + wave;
    const float* row = t2 + (size_t)b * 384;
    float a0 = 0.f, a1 = 0.f, a2 = 0.f;
    #pragma unroll
    for (int kk = 0; kk < 6; kk++) {
        int k = kk * 64 + lane;
        float x = row[k];
        a0 += x * w[k * 3 + 0];
        a1 += x * w[k * 3 + 1];
        a2 += x * w[k * 3 + 2];
    }
    #pragma unroll
    for (int off = 32; off > 0; off >>= 1) {
        a0 += __shfl_down(a0, off);
        a1 += __shfl_down(a1, off);
        a2 += __shfl_down(a2, off);
    }
    if (lane == 0) {
        out[b * 3 + 0] = a0 + bias[0];
        out[b * 3 + 1] = a1 + bias[1];
        out[b * 3 + 2] = a2 + bias[2];
    }
}

extern "C" void kernel_launch(void* const* d_in, const int* in_sizes, int n_in,
                              void* d_out, int out_size, void* d_ws, size_t ws_size,
                              hipStream_t stream)
{
    // Workspace (floats). Total ~41.3M f = 165 MB (237 MB proven safe).
    float* ws    = (float*)d_ws;
    float* h     = ws;                               // 19,200,000
    float* mbfF  = h + (size_t)NN_ * HH;             //  9,600,000 (19.2M bf16)
    float* abfF  = mbfF + (size_t)NN_ * HH / 2;      //  9,600,000 (19.2M bf16)
    float* wpF   = abfF + (size_t)NN_ * HH / 2;      //     27,648
    float* wgpF  = wpF + 27648;                      //     36,864
    float* fc1pF = wgpF + 36864;                     //    294,912 (589,824 bf16)
    float* fc2pF = fc1pF + 294912;                   //    294,912
    float* g3    = fc2pF + 294912;                   //  1,179,648
    int*   rp    = (int*)(g3 + 3 * (size_t)BB * HH); //    200,064 ints
    int*   srcs  = rp + 200064;                      //    400,000 ints
    int*   deg   = srcs + 400000;                    //    200,000 ints
    int*   cur   = deg + 200000;                     //    200,000 ints
    int*   bsum  = cur + 200000;                     //        256 ints
    int*   rpb   = bsum + 256;                       //      4,097 ints

    unsigned short* m_bf   = (unsigned short*)mbfF;
    unsigned short* agg_bf = (unsigned short*)abfF;
    unsigned short* Wp     = (unsigned short*)wpF;
    unsigned short* Wgp    = (unsigned short*)wgpF;
    unsigned short* fc1p   = (unsigned short*)fc1pF;
    unsigned short* fc2p   = (unsigned short*)fc2pF;

    // MLP temps alias h (dead after pooling)
    float* feat = h;
    float* t1   = h + 2 * 1024 * 1024;
    float* t2   = h + 9 * 1024 * 1024;

    for (int c = 0; c < 3; c++) {
        const float* x   = (const float*)d_in[c * 8 + 0];
        const int*   ei  = (const int*)  d_in[c * 8 + 1];
        const int*   bat = (const int*)  d_in[c * 8 + 2];
        const float* W   = (const float*)d_in[c * 8 + 3];
        const float* wih = (const float*)d_in[c * 8 + 4];
        const float* whh = (const float*)d_in[c * 8 + 5];
        const float* bih = (const float*)d_in[c * 8 + 6];
        const float* bhh = (const float*)d_in[c * 8 + 7];

        // CSR build (once per component, reused for all 6 layers)
        hipMemsetAsync(deg, 0, NN_ * sizeof(int), stream);
        deg_k<<<cdiv(EE_, 256), 256, 0, stream>>>(ei, deg);
        scan1_k<<<NB_SCAN, SCAN_B, 0, stream>>>(deg, rp, bsum);
        scan2_k<<<1, 256, 0, stream>>>(bsum);
        scan3_k<<<cdiv(NN_, 256), 256, 0, stream>>>(rp, bsum, cur);
        fill_k<<<cdiv(EE_, 256), 256, 0, stream>>>(ei, cur, srcs);
        brp_k<<<cdiv(NN_, 256), 256, 0, stream>>>(bat, rpb);

        packWp_k<<<cdiv(LL * 3 * 96 * 32, 256), 256, 0, stream>>>(W, Wp);
        packWgp_k<<<cdiv(6 * 384 * 32, 256), 256, 0, stream>>>(wih, whh, Wgp);
        pad_k<<<cdiv(NN_ * HH, 256), 256, 0, stream>>>(x, h);

        for (int l = 0; l < LL; l++) {
            gemm1_mfma<<<NN_ / 64, 256, 0, stream>>>(h, Wp + (size_t)l * 3 * 96 * 32, m_bf);
            agg_csr_k<<<cdiv(NN_ * 12, 256), 256, 0, stream>>>(m_bf, rp, srcs, agg_bf);
            gru_mfma<<<NN_ / 64, 256, 0, stream>>>(agg_bf, Wgp, bih, bhh, h);
        }

        pool_csr_k<<<BB, 128, 0, stream>>>(h, rpb, g3 + (size_t)c * BB * HH);
    }

    const float* fc1_w = (const float*)d_in[24];
    const float* fc1_b = (const float*)d_in[25];
    const float* fc2_w = (const float*)d_in[26];
    const float* fc2_b = (const float*)d_in[27];
    const float* fc3_w = (const float*)d_in[28];
    const float* fc3_b = (const float*)d_in[29];

    packB_k<<<cdiv(384 * 1536, 256), 256, 0, stream>>>(fc1_w, fc1p, 384, 1536);
    packB_k<<<cdiv(1536 * 384, 256), 256, 0, stream>>>(fc2_w, fc2p, 1536, 384);

    feat_k<<<cdiv(BB * HH, 256), 256, 0, stream>>>(
        g3, g3 + (size_t)BB * HH, g3 + 2 * (size_t)BB * HH, feat);
    gemm_mlp_mfma<<<dim3(1536 / 128, BB / 64), 256, 0, stream>>>(
        feat, fc1p, fc1_b, t1, 384, 1536, 1);
    gemm_mlp_mfma<<<dim3(384 / 128, BB / 64), 256, 0, stream>>>(
        t1, fc2p, fc2_b, t2, 1536, 384, 1);
    fc3_k<<<BB / 4, 256, 0, stream>>>(t2, fc3_w, fc3_b, (float*)d_out);
}